// Round 10
// baseline (1499.923 us; speedup 1.0000x reference)
//
#include <hip/hip_runtime.h>
#include <hip/hip_bf16.h>
#include <hip/hip_fp16.h>
#include <stdint.h>

// Problem constants (match reference)
#define NN   10000
#define GG   100
#define NPG  100
#define EE   400000
#define EPG  4000
#define CC   32
#define LM   16
#define SS   4
#define NBES 8
#define NLAYER 3
#define INV_AVG (1.0f/40.0f)
#define NPB  8     // nodes per block (dispatch amortization)

typedef _Float16 f16x8 __attribute__((ext_vector_type(8)));
typedef _Float16 f16x4 __attribute__((ext_vector_type(4)));
typedef float    f32x4 __attribute__((ext_vector_type(4)));

__device__ __forceinline__ float siluf(float x) { return x / (1.0f + __expf(-x)); }
__device__ __forceinline__ int lof(int m) { return (m >= 1) + (m >= 4) + (m >= 9); }

// ---------------------------------------------------------------------------
// Kernel 1: per-edge geometry -> Y[E,16] f32, ef[E,8] f16  (layer-invariant)
// ---------------------------------------------------------------------------
__global__ __launch_bounds__(256) void k_geom(
    const float* __restrict__ pos, const float* __restrict__ cell,
    const int* __restrict__ Sij, const int* __restrict__ eidx,
    const int* __restrict__ batch, float* __restrict__ Y, __half* __restrict__ ef)
{
  int e = blockIdx.x * 256 + threadIdx.x;
  if (e >= EE) return;
  int ia = eidx[e], ja = eidx[EE + e];
  int g = batch[ia];
  float s0 = (float)Sij[e*3+0], s1 = (float)Sij[e*3+1], s2 = (float)Sij[e*3+2];
  const float* cg = cell + g*9;
  float shx = s0*cg[0] + s1*cg[3] + s2*cg[6];
  float shy = s0*cg[1] + s1*cg[4] + s2*cg[7];
  float shz = s0*cg[2] + s1*cg[5] + s2*cg[8];
  float rx = (pos[ja*3+0] - pos[ia*3+0] + shx) / 6.0f;
  float ry = (pos[ja*3+1] - pos[ia*3+1] + shy) / 6.0f;
  float rz = (pos[ja*3+2] - pos[ia*3+2] + shz) / 6.0f;
  float r2 = rx*rx + ry*ry + rz*rz;
  float r  = sqrtf(r2);
  float rs = (r > 1e-9f) ? r : 1e-9f;
  float inv = 1.0f / rs;
  float x = rx*inv, y = ry*inv, z = rz*inv;

  const float s3   = 1.7320508075688772f;
  const float s15  = 3.872983346207417f;
  const float s5h  = 1.118033988749895f;
  const float s15h = 1.9364916731037085f;
  const float s358 = 2.091650066335189f;
  const float s105 = 10.246950765959598f;
  const float s218 = 1.620185174601965f;
  const float s7h  = 1.3228756555322954f;
  const float s105h= 5.123475382979799f;

  float xx = x*x, yy = y*y, zz = z*z;
  float yv[16];
  yv[0]  = 1.0f;
  yv[1]  = s3*x;  yv[2] = s3*y;  yv[3] = s3*z;
  yv[4]  = s15*x*y; yv[5] = s15*y*z; yv[6] = s5h*(3.0f*zz - 1.0f);
  yv[7]  = s15*x*z; yv[8] = s15h*(xx - yy);
  yv[9]  = s358*y*(3.0f*xx - yy);
  yv[10] = s105*x*y*z;
  yv[11] = s218*y*(5.0f*zz - 1.0f);
  yv[12] = s7h*(5.0f*zz*z - 3.0f*z);
  yv[13] = s218*x*(5.0f*zz - 1.0f);
  yv[14] = s105h*z*(xx - yy);
  yv[15] = s358*x*(xx - 3.0f*yy);

  float4* Yp = (float4*)(Y + (size_t)e*16);
  Yp[0] = make_float4(yv[0], yv[1], yv[2], yv[3]);
  Yp[1] = make_float4(yv[4], yv[5], yv[6], yv[7]);
  Yp[2] = make_float4(yv[8], yv[9], yv[10], yv[11]);
  Yp[3] = make_float4(yv[12], yv[13], yv[14], yv[15]);

  float f = 0.0f;
  if (r < 1.0f) f = 1.0f - 6.0f*r2 + 8.0f*r2*r - 3.0f*r2*r2;
  float c1 = 1.4142135623730951f * f * inv;
  float ang = 3.14159265358979323846f * rs;
  float sn = __sinf(ang), cn = __cosf(ang);
  float twoc = 2.0f * cn;
  float sprev = 0.0f, scur = sn;
  union { __half h[8]; uint4 u; } p;
  #pragma unroll
  for (int n1 = 1; n1 <= NBES; ++n1) {
    p.h[n1-1] = __float2half(c1 * scur);
    float snext = twoc * scur - sprev;
    sprev = scur; scur = snext;
  }
  *(uint4*)(ef + (size_t)e*8) = p.u;
}

// ---------------------------------------------------------------------------
// CSR build (layer-invariant)
// ---------------------------------------------------------------------------
__global__ __launch_bounds__(256) void k_csr_zero(int* __restrict__ cnt) {
  int n = blockIdx.x * 256 + threadIdx.x;
  if (n < NN) cnt[n] = 0;
}

__global__ __launch_bounds__(256) void k_csr_count(
    const int* __restrict__ eidx, int* __restrict__ cnt) {
  int e = blockIdx.x * 256 + threadIdx.x;
  if (e < EE) atomicAdd(&cnt[eidx[e]], 1);
}

__global__ __launch_bounds__(128) void k_csr_scan(
    const int* __restrict__ cnt, int* __restrict__ off, int* __restrict__ cursor) {
  __shared__ int s[128];
  int g = blockIdx.x, t = threadIdx.x;
  int own = (t < NPG) ? cnt[g*NPG + t] : 0;
  s[t] = own;
  __syncthreads();
  #pragma unroll
  for (int d = 1; d < 128; d <<= 1) {
    int v = (t >= d) ? s[t-d] : 0;
    __syncthreads();
    s[t] += v;
    __syncthreads();
  }
  if (t < NPG) {
    int o = g*EPG + s[t] - own;
    off[g*NPG + t] = o;
    cursor[g*NPG + t] = o;
    if (g == GG-1 && t == NPG-1) off[NN] = EE;
  }
}

__global__ __launch_bounds__(256) void k_csr_fill(
    const int* __restrict__ eidx, int* __restrict__ cursor, int2* __restrict__ elist) {
  int e = blockIdx.x * 256 + threadIdx.x;
  if (e >= EE) return;
  int ia = eidx[e], ja = eidx[EE + e];
  int pos = atomicAdd(&cursor[ia], 1);
  elist[pos] = make_int2(e, ja);
}

// ---------------------------------------------------------------------------
// Weight conversion (once per call): W2t[l][j][k], W3t[l][j][k] fp16
// ---------------------------------------------------------------------------
__global__ __launch_bounds__(256) void k_wconv(
    const float* __restrict__ W2, const float* __restrict__ W3,
    _Float16* __restrict__ W2t, _Float16* __restrict__ W3t)
{
  int idx = blockIdx.x * 256 + threadIdx.x;
  if (idx < NLAYER*64*64) {
    int l = idx / 4096, rem = idx % 4096, k = rem / 64, j = rem % 64;
    W2t[l*4096 + j*64 + k] = (_Float16)W2[idx];
  }
  if (idx < NLAYER*64*256) {
    int l = idx / 16384, rem = idx % 16384, k = rem / 256, j = rem % 256;
    W3t[l*16384 + j*64 + k] = (_Float16)W3[idx];
  }
}

// ---------------------------------------------------------------------------
// Kernel 2: node init
// ---------------------------------------------------------------------------
__global__ __launch_bounds__(256) void k_init(
    const int* __restrict__ species, const float* __restrict__ W_emb,
    const float* __restrict__ W_xtp, float* __restrict__ h,
    float* __restrict__ xnode, float* __restrict__ node_e)
{
  int idx = blockIdx.x * 256 + threadIdx.x;
  if (idx >= NN*CC) return;
  int n = idx / CC, c = idx % CC;
  int sp = species[n];
  float h0 = W_emb[sp*CC + c];
  float* hp = h + (size_t)n*512 + c*16;
  hp[0] = h0;
  #pragma unroll
  for (int m = 1; m < 16; ++m) hp[m] = 0.0f;
  if (c == 0) {
    float xn = 0.0f;
    for (int c2 = 0; c2 < CC; ++c2) xn += W_emb[sp*CC + c2] * W_xtp[c2*SS + sp];
    xnode[n] = xn;
    node_e[n] = 0.0f;
  }
}

// ---------------------------------------------------------------------------
// Kernel 3 (layer 0 only): hu = h @ Wu, coalesced weight access
// ---------------------------------------------------------------------------
__global__ __launch_bounds__(256) void k_hu(
    const float* __restrict__ h, const float* __restrict__ Wu,
    float* __restrict__ hu)
{
  __shared__ float h_s[512];
  __shared__ float hu_s[512];
  int n = blockIdx.x, t = threadIdx.x;
  h_s[t]       = h[(size_t)n*512 + t];
  h_s[t + 256] = h[(size_t)n*512 + t + 256];
  __syncthreads();
  int lane = t & 63, wv = t >> 6;
  int d = lane & 31, ch = lane >> 5;
  #pragma unroll
  for (int mi = 0; mi < 4; ++mi) {
    int m = wv*4 + mi;
    int l = lof(m);
    const float* wu = Wu + l*1024 + d;
    float u = 0.0f;
    #pragma unroll 4
    for (int cc = 0; cc < 16; ++cc) {
      int c = cc + ch*16;
      u += h_s[c*16 + m] * wu[c*32];
    }
    u += __shfl_xor(u, 32);
    if (ch == 0) hu_s[d*16 + m] = u;
  }
  __syncthreads();
  hu[(size_t)n*512 + t]       = hu_s[t];
  hu[(size_t)n*512 + t + 256] = hu_s[t + 256];
}

// ---------------------------------------------------------------------------
// Kernel 5 (per layer): fused per-node layer (R9 body), NPB nodes per block
// to amortize workgroup-dispatch cost. Grid 1256 (x157 per XCD).
// ---------------------------------------------------------------------------
__global__ __launch_bounds__(256) void k_gather(
    const int2* __restrict__ elist, const int* __restrict__ off,
    const float* __restrict__ Y, const __half* __restrict__ ef,
    const float* __restrict__ W1, const float* __restrict__ b1,
    const _Float16* __restrict__ W2t, const float* __restrict__ b2,
    const _Float16* __restrict__ W3t, const float* __restrict__ hu_in,
    const int* __restrict__ species, const float* __restrict__ xnode,
    const float* __restrict__ Wd, const float* __restrict__ Wsc,
    const float* __restrict__ Wr1, const float* __restrict__ br1,
    const float* __restrict__ Wr2, float* __restrict__ node_e,
    const float* __restrict__ Wu_next, float* __restrict__ hu_out,
    float* __restrict__ h, int has_next)
{
  // 13824 B pool:
  //  phase1: hm1 f16[16][72] @0, hm2 f16[16][72] @2304, elw int2[4][16] @4608,
  //          rw f16[4][16][68] @5120
  //  phase2: al f32[512] @0, h2/out f32[512] @2048 (overlay; barrier-guarded)
  __shared__ float pool[3456];
  _Float16* hm1 = (_Float16*)pool;
  _Float16* hm2 = ((_Float16*)pool) + 16*72;
  int2* elw_all = (int2*)(pool + 1152);
  _Float16* rw_all = (_Float16*)(pool + 1280);
  float* al_s = pool;
  float* h2_s = pool + 512;

  int b = blockIdx.x, t = threadIdx.x;
  int lb = (b & 7) * 157 + (b >> 3);    // XCD-locality swizzle, 8x157 >= 1250
  if (lb >= NN/NPB) return;

  int lane = t & 63, wv = t >> 6;
  int ln15 = lane & 15, quad = lane >> 4;
  _Float16* rww = rw_all + wv*(16*68);
  int2* elw = elw_all + wv*16;

  // message mapping (wave-local: c in [wv*8, wv*8+8))
  int cl = lane >> 3, m0 = (lane & 7) * 2;
  int c = wv*8 + cl, cl4 = cl*4;
  int l0 = lof(m0), l1 = lof(m0 + 1);

  // GEMM1 mapping (node-independent)
  int j1 = wv*16 + quad*4;
  float4 b1v = *(const float4*)(b1 + j1);
  float  b2v = b2[wv*16 + ln15];
  int d = lane & 31, ch = lane >> 5;

  for (int ni = 0; ni < NPB; ++ni) {
    int n = lb*NPB + ni;
    int beg = off[n], deg = off[n+1] - beg;

    // stage this node's h in registers (LDS busy until epilogue)
    float hreg0 = h[(size_t)n*512 + t];
    float hreg1 = h[(size_t)n*512 + t + 256];

    float acc0 = 0.0f, acc1 = 0.0f;

    // ---- prefetch tile 0 (elist in regs, ef via shfl-broadcast edge id)
    int2 eln_cur = make_int2(0, 0);
    uint4 efq_cur = make_uint4(0,0,0,0);
    if (deg > 0) {
      int idx = lane;
      int cidx = idx < deg ? idx : deg - 1;
      if (lane < 16) eln_cur = elist[beg + cidx];
      int e1 = __shfl(eln_cur.x, ln15);
      efq_cur = *(const uint4*)(ef + (size_t)e1*8);
    }

    for (int base = 0; base < deg; base += 16) {
      int cnt = min(16, deg - base);
      if (lane < 16) elw[lane] = eln_cur;

      // ---- GEMM1: ef(8) -> hm1(64), fp32 VALU, silu, fp16 out (cooperative)
      {
        union { uint4 u; __half hh[8]; } efv; efv.u = efq_cur;
        float a0 = b1v.x, a1 = b1v.y, a2 = b1v.z, a3 = b1v.w;
        #pragma unroll
        for (int k = 0; k < 8; ++k) {
          float ev = __half2float(efv.hh[k]);
          const float4 w = *(const float4*)(W1 + k*64 + j1);
          a0 += ev*w.x; a1 += ev*w.y; a2 += ev*w.z; a3 += ev*w.w;
        }
        f16x4 pk;
        pk[0] = (_Float16)siluf(a0);
        pk[1] = (_Float16)siluf(a1);
        pk[2] = (_Float16)siluf(a2);
        pk[3] = (_Float16)siluf(a3);
        *(f16x4*)&hm1[ln15*72 + j1] = pk;
      }
      __syncthreads();   // B1: hm1 complete

      // ---- GEMM2: hm1(64) -> hm2(64), MFMA; wave owns cols wv*16..+15
      {
        f16x8 a20 = *(const f16x8*)(hm1 + ln15*72 + quad*8);
        f16x8 a21 = *(const f16x8*)(hm1 + ln15*72 + 32 + quad*8);
        int col = wv*16 + ln15;
        f32x4 dd = {0.f, 0.f, 0.f, 0.f};
        dd = __builtin_amdgcn_mfma_f32_16x16x32_f16(a20, *(const f16x8*)(W2t + (size_t)col*64 + quad*8), dd, 0, 0, 0);
        dd = __builtin_amdgcn_mfma_f32_16x16x32_f16(a21, *(const f16x8*)(W2t + (size_t)col*64 + 32 + quad*8), dd, 0, 0, 0);
        #pragma unroll
        for (int r = 0; r < 4; ++r)
          hm2[(quad*4 + r)*72 + col] = (_Float16)siluf(dd[r] + b2v);
      }
      __syncthreads();   // B2: hm2 complete

      // ---- GEMM3: hm2(64) -> this wave's 64 rw cols (wave-local), fp16 slab
      {
        f16x8 a30 = *(const f16x8*)(hm2 + ln15*72 + quad*8);
        f16x8 a31 = *(const f16x8*)(hm2 + ln15*72 + 32 + quad*8);
        #pragma unroll
        for (int cg = 0; cg < 4; ++cg) {
          int colg = (cg < 2) ? (wv*32 + cg*16 + ln15)
                              : (128 + wv*32 + (cg-2)*16 + ln15);
          f32x4 dd = {0.f, 0.f, 0.f, 0.f};
          dd = __builtin_amdgcn_mfma_f32_16x16x32_f16(a30, *(const f16x8*)(W3t + (size_t)colg*64 + quad*8), dd, 0, 0, 0);
          dd = __builtin_amdgcn_mfma_f32_16x16x32_f16(a31, *(const f16x8*)(W3t + (size_t)colg*64 + 32 + quad*8), dd, 0, 0, 0);
          #pragma unroll
          for (int r = 0; r < 4; ++r)
            rww[(quad*4 + r)*68 + cg*16 + ln15] = (_Float16)dd[r];
        }
      }

      // ---- prefetch next tile's elist + ef (overlaps message loop)
      int2 eln_nxt = eln_cur; uint4 efq_nxt = efq_cur;
      if (base + 16 < deg) {
        int idx = base + 16 + lane;
        int cidx = idx < deg ? idx : deg - 1;
        if (lane < 16) eln_nxt = elist[beg + cidx];
        int e1 = __shfl(eln_nxt.x, ln15);
        efq_nxt = *(const uint4*)(ef + (size_t)e1*8);
      }

      // ---- message accumulate (wave-local rw reads, no barrier)
      #pragma unroll 4
      for (int i = 0; i < cnt; ++i) {
        int2 ed = elw[i];
        const float* hup = hu_in + (size_t)ed.y*512 + c*16;
        float  hj0 = hup[0];
        float2 hjm = *(const float2*)(hup + m0);
        float2 Ym  = *(const float2*)(Y + (size_t)ed.x*16 + m0);
        float w00 = (float)rww[i*68 + cl4 + l0];
        float w01 = (float)rww[i*68 + cl4 + l1];
        float w10 = (float)rww[i*68 + 32 + cl4 + l0];
        float w11 = (float)rww[i*68 + 32 + cl4 + l1];
        acc0 += w00 * Ym.x * hj0 + w10 * hjm.x;
        acc1 += w01 * Ym.y * hj0 + w11 * hjm.y;
      }

      eln_cur = eln_nxt; efq_cur = efq_nxt;
    }

    __syncthreads();   // tile phase done -> phase2 overlay safe

    // ---- agg + h into phase2 LDS
    al_s[c*16 + m0]     = acc0 * INV_AVG;
    al_s[c*16 + m0 + 1] = acc1 * INV_AVG;
    h2_s[t]       = hreg0;
    h2_s[t + 256] = hreg1;
    __syncthreads();

    // ---- update epilogue (coalesced weights, wave-uniform l)
    int sp = species[n];
    float xn = xnode[n];
    #pragma unroll
    for (int mi = 0; mi < 4; ++mi) {
      int m = wv*4 + mi;
      int l = lof(m);
      const float* wd  = Wd  + l*1024 + d;
      const float* wsc = Wsc + l*4096 + sp*32 + d;
      float a = 0.0f, s = 0.0f;
      #pragma unroll 4
      for (int cc = 0; cc < 16; ++cc) {
        int c2 = cc + ch*16;
        a += al_s[c2*16 + m] * wd[c2*32];
        s += h2_s[c2*16 + m] * wsc[c2*128];
      }
      a += __shfl_xor(a, 32);
      s += __shfl_xor(s, 32);
      float hn = a*xn + s;
      if (ch == 0) h2_s[d*16 + m] = hn;       // out overlay (wave-excl col)
      if (has_next) {
        const float* wu = Wu_next + l*1024 + d;
        float u = 0.0f;
        #pragma unroll 4
        for (int cc = 0; cc < 16; ++cc) {
          int c2 = cc + ch*16;
          u += h2_s[c2*16 + m] * wu[c2*32];    // reads out (same wave wrote)
        }
        u += __shfl_xor(u, 32);
        if (ch == 0) al_s[d*16 + m] = u;      // hu overlay (wave-excl col)
      }
    }

    // readout (wave 0 reads its own out m=0 column)
    if (t < 64) {
      float pre = br1[t];
      #pragma unroll 4
      for (int cc = 0; cc < CC; ++cc) pre += h2_s[cc*16] * Wr1[cc*64 + t];
      float v = siluf(pre) * Wr2[t];
      #pragma unroll
      for (int off2 = 32; off2 > 0; off2 >>= 1) v += __shfl_down(v, off2);
      if (t == 0) node_e[n] += siluf(v);
    }
    __syncthreads();   // out/hu complete

    h[(size_t)n*512 + t]       = h2_s[t];
    h[(size_t)n*512 + t + 256] = h2_s[t + 256];
    if (has_next) {
      hu_out[(size_t)n*512 + t]       = al_s[t];
      hu_out[(size_t)n*512 + t + 256] = al_s[t + 256];
    }
    __syncthreads();   // writeback reads done -> next node may overwrite LDS
  }
}

// ---------------------------------------------------------------------------
// Kernel 7: per-graph sum of node energies
// ---------------------------------------------------------------------------
__global__ __launch_bounds__(128) void k_out(
    const float* __restrict__ node_e, float* __restrict__ out)
{
  int g = blockIdx.x, t = threadIdx.x;
  float v = (t < NPG) ? node_e[g*NPG + t] : 0.0f;
  #pragma unroll
  for (int off2 = 32; off2 > 0; off2 >>= 1) v += __shfl_down(v, off2);
  __shared__ float r2[2];
  if ((t & 63) == 0) r2[t >> 6] = v;
  __syncthreads();
  if (t == 0) out[g] = r2[0] + r2[1];
}

// Diagnostic: if workspace too small, report its size (MB) via absmax
__global__ void k_dbg(float* __restrict__ out, float v) {
  int i = blockIdx.x * 64 + threadIdx.x;
  if (i < GG) out[i] = v;
}

// ---------------------------------------------------------------------------
extern "C" void kernel_launch(void* const* d_in, const int* in_sizes, int n_in,
                              void* d_out, int out_size, void* d_ws, size_t ws_size,
                              hipStream_t stream)
{
  const float* positions = (const float*)d_in[0];
  const float* cell      = (const float*)d_in[1];
  const int*   Sij       = (const int*)d_in[2];
  const int*   eidx      = (const int*)d_in[3];
  const int*   species   = (const int*)d_in[4];
  const int*   batch     = (const int*)d_in[5];
  const float* W_emb     = (const float*)d_in[6];
  const float* W_xtp     = (const float*)d_in[7];
  const float* W_up      = (const float*)d_in[8];
  const float* W1        = (const float*)d_in[9];
  const float* b1        = (const float*)d_in[10];
  const float* W2        = (const float*)d_in[11];
  const float* b2        = (const float*)d_in[12];
  const float* W3        = (const float*)d_in[13];
  const float* W_down    = (const float*)d_in[14];
  const float* W_sc      = (const float*)d_in[15];
  const float* Wr1       = (const float*)d_in[16];
  const float* br1       = (const float*)d_in[17];
  const float* Wr2       = (const float*)d_in[18];
  float* out = (float*)d_out;
  (void)in_sizes; (void)n_in; (void)out_size;

  const size_t NEED = 100000000;
  if (ws_size < NEED) {
    k_dbg<<<dim3(2), dim3(64), 0, stream>>>(out, (float)(ws_size >> 20));
    return;
  }

  char* ws = (char*)d_ws;
  size_t off = 0;
  auto alloc = [&](size_t bytes) -> void* {
    void* p = ws + off;
    off += (bytes + 255) & ~(size_t)255;
    return p;
  };
  float*     Yb      = (float*)alloc((size_t)EE*16*4);   // 25.6 MB
  __half*    efb     = (__half*)alloc((size_t)EE*8*2);   //  6.4 MB
  float*     hb      = (float*)alloc((size_t)NN*512*4);  // 20.5 MB
  float*     huA     = (float*)alloc((size_t)NN*512*4);  // 20.5 MB
  float*     huB     = (float*)alloc((size_t)NN*512*4);  // 20.5 MB
  float*     xnodeb  = (float*)alloc((size_t)NN*4);
  float*     node_eb = (float*)alloc((size_t)NN*4);
  int*       offb    = (int*)alloc((size_t)(NN+1)*4);
  int*       curb    = (int*)alloc((size_t)NN*4);
  int2*      elistb  = (int2*)alloc((size_t)EE*8);       //  3.2 MB
  _Float16*  W2tb    = (_Float16*)alloc((size_t)NLAYER*64*64*2);
  _Float16*  W3tb    = (_Float16*)alloc((size_t)NLAYER*64*256*2);

  dim3 blk(256);
  k_geom<<<dim3((EE + 255)/256), blk, 0, stream>>>(positions, cell, Sij, eidx, batch, Yb, efb);
  k_init<<<dim3((NN*CC + 255)/256), blk, 0, stream>>>(species, W_emb, W_xtp, hb, xnodeb, node_eb);
  k_wconv<<<dim3((NLAYER*64*256 + 255)/256), blk, 0, stream>>>(W2, W3, W2tb, W3tb);

  // CSR build (layer-invariant)
  k_csr_zero <<<dim3((NN + 255)/256), blk, 0, stream>>>(curb);
  k_csr_count<<<dim3((EE + 255)/256), blk, 0, stream>>>(eidx, curb);
  k_csr_scan <<<dim3(GG), dim3(128), 0, stream>>>(curb, offb, curb);
  k_csr_fill <<<dim3((EE + 255)/256), blk, 0, stream>>>(eidx, curb, elistb);

  // layer 0 hu from initial h
  k_hu<<<dim3(NN), blk, 0, stream>>>(hb, W_up + 0*4096, huA);

  float* hin = huA; float* hout = huB;
  for (int layer = 0; layer < NLAYER; ++layer) {
    int has_next = (layer + 1 < NLAYER) ? 1 : 0;
    k_gather<<<dim3(1256), blk, 0, stream>>>(elistb, offb, Yb, efb,
        W1 + layer*NBES*64, b1 + layer*64,
        W2tb + layer*4096, b2 + layer*64,
        W3tb + layer*16384, hin,
        species, xnodeb,
        W_down + layer*4096, W_sc + layer*16384,
        Wr1 + layer*CC*64, br1 + layer*64, Wr2 + layer*64, node_eb,
        W_up + (has_next ? (layer+1)*4096 : 0), hout, hb, has_next);
    float* tmp = hin; hin = hout; hout = tmp;
  }
  k_out<<<dim3(GG), dim3(128), 0, stream>>>(node_eb, out);
}

// Round 11
// 1179.044 us; speedup vs baseline: 1.2722x; 1.2722x over previous
//
#include <hip/hip_runtime.h>
#include <hip/hip_bf16.h>
#include <hip/hip_fp16.h>
#include <stdint.h>

// Problem constants (match reference)
#define NN   10000
#define GG   100
#define NPG  100
#define EE   400000
#define EPG  4000
#define CC   32
#define LM   16
#define SS   4
#define NBES 8
#define NLAYER 3
#define INV_AVG (1.0f/40.0f)

typedef _Float16 f16x8 __attribute__((ext_vector_type(8)));
typedef _Float16 f16x4 __attribute__((ext_vector_type(4)));
typedef float    f32x4 __attribute__((ext_vector_type(4)));

__device__ __forceinline__ float siluf(float x) { return x / (1.0f + __expf(-x)); }
__device__ __forceinline__ int lof(int m) { return (m >= 1) + (m >= 4) + (m >= 9); }

// ---------------------------------------------------------------------------
// Kernel 1: per-edge geometry -> Y[E,16] f32, ef[E,8] f16  (layer-invariant)
// ---------------------------------------------------------------------------
__global__ __launch_bounds__(256) void k_geom(
    const float* __restrict__ pos, const float* __restrict__ cell,
    const int* __restrict__ Sij, const int* __restrict__ eidx,
    const int* __restrict__ batch, float* __restrict__ Y, __half* __restrict__ ef)
{
  int e = blockIdx.x * 256 + threadIdx.x;
  if (e >= EE) return;
  int ia = eidx[e], ja = eidx[EE + e];
  int g = batch[ia];
  float s0 = (float)Sij[e*3+0], s1 = (float)Sij[e*3+1], s2 = (float)Sij[e*3+2];
  const float* cg = cell + g*9;
  float shx = s0*cg[0] + s1*cg[3] + s2*cg[6];
  float shy = s0*cg[1] + s1*cg[4] + s2*cg[7];
  float shz = s0*cg[2] + s1*cg[5] + s2*cg[8];
  float rx = (pos[ja*3+0] - pos[ia*3+0] + shx) / 6.0f;
  float ry = (pos[ja*3+1] - pos[ia*3+1] + shy) / 6.0f;
  float rz = (pos[ja*3+2] - pos[ia*3+2] + shz) / 6.0f;
  float r2 = rx*rx + ry*ry + rz*rz;
  float r  = sqrtf(r2);
  float rs = (r > 1e-9f) ? r : 1e-9f;
  float inv = 1.0f / rs;
  float x = rx*inv, y = ry*inv, z = rz*inv;

  const float s3   = 1.7320508075688772f;
  const float s15  = 3.872983346207417f;
  const float s5h  = 1.118033988749895f;
  const float s15h = 1.9364916731037085f;
  const float s358 = 2.091650066335189f;
  const float s105 = 10.246950765959598f;
  const float s218 = 1.620185174601965f;
  const float s7h  = 1.3228756555322954f;
  const float s105h= 5.123475382979799f;

  float xx = x*x, yy = y*y, zz = z*z;
  float yv[16];
  yv[0]  = 1.0f;
  yv[1]  = s3*x;  yv[2] = s3*y;  yv[3] = s3*z;
  yv[4]  = s15*x*y; yv[5] = s15*y*z; yv[6] = s5h*(3.0f*zz - 1.0f);
  yv[7]  = s15*x*z; yv[8] = s15h*(xx - yy);
  yv[9]  = s358*y*(3.0f*xx - yy);
  yv[10] = s105*x*y*z;
  yv[11] = s218*y*(5.0f*zz - 1.0f);
  yv[12] = s7h*(5.0f*zz*z - 3.0f*z);
  yv[13] = s218*x*(5.0f*zz - 1.0f);
  yv[14] = s105h*z*(xx - yy);
  yv[15] = s358*x*(xx - 3.0f*yy);

  float4* Yp = (float4*)(Y + (size_t)e*16);
  Yp[0] = make_float4(yv[0], yv[1], yv[2], yv[3]);
  Yp[1] = make_float4(yv[4], yv[5], yv[6], yv[7]);
  Yp[2] = make_float4(yv[8], yv[9], yv[10], yv[11]);
  Yp[3] = make_float4(yv[12], yv[13], yv[14], yv[15]);

  float f = 0.0f;
  if (r < 1.0f) f = 1.0f - 6.0f*r2 + 8.0f*r2*r - 3.0f*r2*r2;
  float c1 = 1.4142135623730951f * f * inv;
  float ang = 3.14159265358979323846f * rs;
  float sn = __sinf(ang), cn = __cosf(ang);
  float twoc = 2.0f * cn;
  float sprev = 0.0f, scur = sn;
  union { __half h[8]; uint4 u; } p;
  #pragma unroll
  for (int n1 = 1; n1 <= NBES; ++n1) {
    p.h[n1-1] = __float2half(c1 * scur);
    float snext = twoc * scur - sprev;
    sprev = scur; scur = snext;
  }
  *(uint4*)(ef + (size_t)e*8) = p.u;
}

// ---------------------------------------------------------------------------
// CSR build (layer-invariant)
// ---------------------------------------------------------------------------
__global__ __launch_bounds__(256) void k_csr_zero(int* __restrict__ cnt) {
  int n = blockIdx.x * 256 + threadIdx.x;
  if (n < NN) cnt[n] = 0;
}

__global__ __launch_bounds__(256) void k_csr_count(
    const int* __restrict__ eidx, int* __restrict__ cnt) {
  int e = blockIdx.x * 256 + threadIdx.x;
  if (e < EE) atomicAdd(&cnt[eidx[e]], 1);
}

__global__ __launch_bounds__(128) void k_csr_scan(
    const int* __restrict__ cnt, int* __restrict__ off, int* __restrict__ cursor) {
  __shared__ int s[128];
  int g = blockIdx.x, t = threadIdx.x;
  int own = (t < NPG) ? cnt[g*NPG + t] : 0;
  s[t] = own;
  __syncthreads();
  #pragma unroll
  for (int d = 1; d < 128; d <<= 1) {
    int v = (t >= d) ? s[t-d] : 0;
    __syncthreads();
    s[t] += v;
    __syncthreads();
  }
  if (t < NPG) {
    int o = g*EPG + s[t] - own;
    off[g*NPG + t] = o;
    cursor[g*NPG + t] = o;
    if (g == GG-1 && t == NPG-1) off[NN] = EE;
  }
}

__global__ __launch_bounds__(256) void k_csr_fill(
    const int* __restrict__ eidx, int* __restrict__ cursor, int2* __restrict__ elist) {
  int e = blockIdx.x * 256 + threadIdx.x;
  if (e >= EE) return;
  int ia = eidx[e], ja = eidx[EE + e];
  int pos = atomicAdd(&cursor[ia], 1);
  elist[pos] = make_int2(e, ja);
}

// ---------------------------------------------------------------------------
// Weight conversion (once per call): W2t[l][j][k], W3t[l][j][k] fp16
// ---------------------------------------------------------------------------
__global__ __launch_bounds__(256) void k_wconv(
    const float* __restrict__ W2, const float* __restrict__ W3,
    _Float16* __restrict__ W2t, _Float16* __restrict__ W3t)
{
  int idx = blockIdx.x * 256 + threadIdx.x;
  if (idx < NLAYER*64*64) {
    int l = idx / 4096, rem = idx % 4096, k = rem / 64, j = rem % 64;
    W2t[l*4096 + j*64 + k] = (_Float16)W2[idx];
  }
  if (idx < NLAYER*64*256) {
    int l = idx / 16384, rem = idx % 16384, k = rem / 256, j = rem % 256;
    W3t[l*16384 + j*64 + k] = (_Float16)W3[idx];
  }
}

// ---------------------------------------------------------------------------
// Kernel 2: node init
// ---------------------------------------------------------------------------
__global__ __launch_bounds__(256) void k_init(
    const int* __restrict__ species, const float* __restrict__ W_emb,
    const float* __restrict__ W_xtp, float* __restrict__ h,
    float* __restrict__ xnode, float* __restrict__ node_e)
{
  int idx = blockIdx.x * 256 + threadIdx.x;
  if (idx >= NN*CC) return;
  int n = idx / CC, c = idx % CC;
  int sp = species[n];
  float h0 = W_emb[sp*CC + c];
  float* hp = h + (size_t)n*512 + c*16;
  hp[0] = h0;
  #pragma unroll
  for (int m = 1; m < 16; ++m) hp[m] = 0.0f;
  if (c == 0) {
    float xn = 0.0f;
    for (int c2 = 0; c2 < CC; ++c2) xn += W_emb[sp*CC + c2] * W_xtp[c2*SS + sp];
    xnode[n] = xn;
    node_e[n] = 0.0f;
  }
}

// ---------------------------------------------------------------------------
// Kernel 3 (layer 0 only): hu = h @ Wu, coalesced weight access
// ---------------------------------------------------------------------------
__global__ __launch_bounds__(256) void k_hu(
    const float* __restrict__ h, const float* __restrict__ Wu,
    float* __restrict__ hu)
{
  __shared__ float h_s[512];
  __shared__ float hu_s[512];
  int n = blockIdx.x, t = threadIdx.x;
  h_s[t]       = h[(size_t)n*512 + t];
  h_s[t + 256] = h[(size_t)n*512 + t + 256];
  __syncthreads();
  int lane = t & 63, wv = t >> 6;
  int d = lane & 31, ch = lane >> 5;
  #pragma unroll
  for (int mi = 0; mi < 4; ++mi) {
    int m = wv*4 + mi;
    int l = lof(m);
    const float* wu = Wu + l*1024 + d;
    float u = 0.0f;
    #pragma unroll 4
    for (int cc = 0; cc < 16; ++cc) {
      int c = cc + ch*16;
      u += h_s[c*16 + m] * wu[c*32];
    }
    u += __shfl_xor(u, 32);
    if (ch == 0) hu_s[d*16 + m] = u;
  }
  __syncthreads();
  hu[(size_t)n*512 + t]       = hu_s[t];
  hu[(size_t)n*512 + t + 256] = hu_s[t + 256];
}

// ---------------------------------------------------------------------------
// Kernel 4 (per layer): edge MLP, edge-major streaming:
// ef(8) -> hm1(64) fp32 VALU -> hm2(64) MFMA, silu, fp16 global.
// 64 edges/block (16/wave), wave-autonomous, XCD-swizzled.
// ---------------------------------------------------------------------------
__global__ __launch_bounds__(256) void k_mlp(
    const __half* __restrict__ ef, const float* __restrict__ W1,
    const float* __restrict__ b1, const _Float16* __restrict__ W2t,
    const float* __restrict__ b2, __half* __restrict__ hm2)
{
  __shared__ _Float16 hm1_s[4][16*72];
  int b = blockIdx.x, t = threadIdx.x;
  int eb = (b & 7) * 782 + (b >> 3);
  if (eb >= EE/64) return;
  int wv = t >> 6, lane = t & 63;
  int ln15 = lane & 15, quad = lane >> 4;
  _Float16* hm1 = hm1_s[wv];
  size_t e16 = (size_t)eb*64 + wv*16;

  union { uint4 u; __half hh[8]; } efv;
  efv.u = *(const uint4*)(ef + (e16 + ln15)*8);
  float ev[8];
  #pragma unroll
  for (int k = 0; k < 8; ++k) ev[k] = __half2float(efv.hh[k]);
  #pragma unroll
  for (int p = 0; p < 4; ++p) {
    int j0 = p*16 + quad*4;
    float4 a = *(const float4*)(b1 + j0);
    #pragma unroll
    for (int k = 0; k < 8; ++k) {
      const float4 w = *(const float4*)(W1 + k*64 + j0);
      a.x += ev[k]*w.x; a.y += ev[k]*w.y; a.z += ev[k]*w.z; a.w += ev[k]*w.w;
    }
    f16x4 pk;
    pk[0] = (_Float16)siluf(a.x);
    pk[1] = (_Float16)siluf(a.y);
    pk[2] = (_Float16)siluf(a.z);
    pk[3] = (_Float16)siluf(a.w);
    *(f16x4*)&hm1[ln15*72 + j0] = pk;
  }

  f16x8 a0 = *(const f16x8*)(hm1 + ln15*72 + quad*8);
  f16x8 a1 = *(const f16x8*)(hm1 + ln15*72 + 32 + quad*8);
  #pragma unroll
  for (int cg = 0; cg < 4; ++cg) {
    int col = cg*16 + ln15;
    f32x4 d = {0.f, 0.f, 0.f, 0.f};
    d = __builtin_amdgcn_mfma_f32_16x16x32_f16(a0, *(const f16x8*)(W2t + (size_t)col*64 + quad*8), d, 0, 0, 0);
    d = __builtin_amdgcn_mfma_f32_16x16x32_f16(a1, *(const f16x8*)(W2t + (size_t)col*64 + 32 + quad*8), d, 0, 0, 0);
    float bb = b2[col];
    #pragma unroll
    for (int r = 0; r < 4; ++r)
      hm2[(e16 + quad*4 + r)*64 + col] = __float2half(siluf(d[r] + bb));
  }
}

// ---------------------------------------------------------------------------
// Kernel 5 (per layer): block-per-node gather, ZERO barriers in the tile loop.
// Per 32-edge tile (per wave): A-frags straight from global hm2 (prefetched
// one tile ahead; edge list held in regs, broadcast via shfl), 16 wave-local
// GEMM3 MFMAs -> fp16 rw slab, message accumulate. Epilogue as R9 (3 barriers).
// LDS 17.4 KB.
// ---------------------------------------------------------------------------
__global__ __launch_bounds__(256) void k_gather(
    const int2* __restrict__ elist, const int* __restrict__ off,
    const float* __restrict__ Y, const __half* __restrict__ hm2,
    const _Float16* __restrict__ W3t, const float* __restrict__ hu_in,
    const int* __restrict__ species, const float* __restrict__ xnode,
    const float* __restrict__ Wd, const float* __restrict__ Wsc,
    const float* __restrict__ Wr1, const float* __restrict__ br1,
    const float* __restrict__ Wr2, float* __restrict__ node_e,
    const float* __restrict__ Wu_next, float* __restrict__ hu_out,
    float* __restrict__ h, int has_next)
{
  // rw slab: 4 waves x 32 rows x 68 halfs = 17408 B.
  // Epilogue overlays al(2KB)+out/h2(2KB) on the front (barrier-guarded).
  __shared__ _Float16 rw_all[4][32*68];
  float* al_s = (float*)&rw_all[0][0];
  float* h2_s = al_s + 512;

  int b = blockIdx.x, t = threadIdx.x;
  int n = (b & 7) * (NN/8) + (b >> 3);   // XCD-locality swizzle
  int beg = off[n], deg = off[n+1] - beg;

  int lane = t & 63, wv = t >> 6;
  int ln15 = lane & 15, quad = lane >> 4;
  _Float16* rww = rw_all[wv];
  const _Float16* hm2h = (const _Float16*)hm2;

  // stage this node's h in registers (LDS busy until epilogue)
  float hreg0 = h[(size_t)n*512 + t];
  float hreg1 = h[(size_t)n*512 + t + 256];

  // message mapping (wave-local: c in [wv*8, wv*8+8))
  int cl = lane >> 3, m0 = (lane & 7) * 2;
  int c = wv*8 + cl, cl4 = cl*4;
  int l0 = lof(m0), l1 = lof(m0 + 1);
  float acc0 = 0.0f, acc1 = 0.0f;

  // ---- prefetch tile 0: edge list (lanes 0..31) + A-frags from global hm2
  int2 el_cur = make_int2(0, 0);
  f16x8 aA0 = {}, aA1 = {}, aB0 = {}, aB1 = {};
  if (deg > 0) {
    int idx = lane < deg ? lane : deg - 1;
    el_cur = elist[beg + idx];
    int eA = __shfl(el_cur.x, ln15);
    int eB = __shfl(el_cur.x, 16 + ln15);
    aA0 = *(const f16x8*)(hm2h + (size_t)eA*64 + quad*8);
    aA1 = *(const f16x8*)(hm2h + (size_t)eA*64 + 32 + quad*8);
    aB0 = *(const f16x8*)(hm2h + (size_t)eB*64 + quad*8);
    aB1 = *(const f16x8*)(hm2h + (size_t)eB*64 + 32 + quad*8);
  }

  for (int base = 0; base < deg; base += 32) {
    int cnt = min(32, deg - base);

    // ---- GEMM3: 16 MFMA, wave-local columns; rows 0-15 (A), 16-31 (B)
    #pragma unroll
    for (int cg = 0; cg < 4; ++cg) {
      int colg = (cg < 2) ? (wv*32 + cg*16 + ln15)
                          : (128 + wv*32 + (cg-2)*16 + ln15);
      f16x8 b0 = *(const f16x8*)(W3t + (size_t)colg*64 + quad*8);
      f16x8 b1v = *(const f16x8*)(W3t + (size_t)colg*64 + 32 + quad*8);
      f32x4 dA = {0.f, 0.f, 0.f, 0.f};
      dA = __builtin_amdgcn_mfma_f32_16x16x32_f16(aA0, b0, dA, 0, 0, 0);
      dA = __builtin_amdgcn_mfma_f32_16x16x32_f16(aA1, b1v, dA, 0, 0, 0);
      f32x4 dB = {0.f, 0.f, 0.f, 0.f};
      dB = __builtin_amdgcn_mfma_f32_16x16x32_f16(aB0, b0, dB, 0, 0, 0);
      dB = __builtin_amdgcn_mfma_f32_16x16x32_f16(aB1, b1v, dB, 0, 0, 0);
      #pragma unroll
      for (int r = 0; r < 4; ++r) {
        rww[(quad*4 + r)*68 + cg*16 + ln15]      = (_Float16)dA[r];
        rww[(16 + quad*4 + r)*68 + cg*16 + ln15] = (_Float16)dB[r];
      }
    }

    // ---- prefetch next tile (elist + A-frags), overlaps message loop
    int2 el_nxt = el_cur;
    f16x8 nA0 = aA0, nA1 = aA1, nB0 = aB0, nB1 = aB1;
    if (base + 32 < deg) {
      int idx = base + 32 + lane;
      if (idx >= deg) idx = deg - 1;
      el_nxt = elist[beg + idx];
      int eA = __shfl(el_nxt.x, ln15);
      int eB = __shfl(el_nxt.x, 16 + ln15);
      nA0 = *(const f16x8*)(hm2h + (size_t)eA*64 + quad*8);
      nA1 = *(const f16x8*)(hm2h + (size_t)eA*64 + 32 + quad*8);
      nB0 = *(const f16x8*)(hm2h + (size_t)eB*64 + quad*8);
      nB1 = *(const f16x8*)(hm2h + (size_t)eB*64 + 32 + quad*8);
    }

    // ---- message accumulate (edge list broadcast from regs via shfl)
    #pragma unroll 4
    for (int i = 0; i < cnt; ++i) {
      int ex = __shfl(el_cur.x, i);
      int ja = __shfl(el_cur.y, i);
      const float* hup = hu_in + (size_t)ja*512 + c*16;
      float2 hjm = *(const float2*)(hup + m0);
      float  hj0 = __shfl(hjm.x, lane & 56);  // from this c's m0=0 lane
      float2 Ym  = *(const float2*)(Y + (size_t)ex*16 + m0);
      float w00 = (float)rww[i*68 + cl4 + l0];
      float w01 = (float)rww[i*68 + cl4 + l1];
      float w10 = (float)rww[i*68 + 32 + cl4 + l0];
      float w11 = (float)rww[i*68 + 32 + cl4 + l1];
      acc0 += w00 * Ym.x * hj0 + w10 * hjm.x;
      acc1 += w01 * Ym.y * hj0 + w11 * hjm.y;
    }

    el_cur = el_nxt;
    aA0 = nA0; aA1 = nA1; aB0 = nB0; aB1 = nB1;
  }

  __syncthreads();   // tile phase done -> overlay safe

  // ---- agg + h into phase2 LDS
  al_s[c*16 + m0]     = acc0 * INV_AVG;
  al_s[c*16 + m0 + 1] = acc1 * INV_AVG;
  h2_s[t]       = hreg0;
  h2_s[t + 256] = hreg1;
  __syncthreads();

  // ---- update epilogue (coalesced weights, wave-uniform l)
  int sp = species[n];
  float xn = xnode[n];
  int d = lane & 31, ch = lane >> 5;
  #pragma unroll
  for (int mi = 0; mi < 4; ++mi) {
    int m = wv*4 + mi;
    int l = lof(m);
    const float* wd  = Wd  + l*1024 + d;
    const float* wsc = Wsc + l*4096 + sp*32 + d;
    float a = 0.0f, s = 0.0f;
    #pragma unroll 4
    for (int cc = 0; cc < 16; ++cc) {
      int c2 = cc + ch*16;
      a += al_s[c2*16 + m] * wd[c2*32];
      s += h2_s[c2*16 + m] * wsc[c2*128];
    }
    a += __shfl_xor(a, 32);
    s += __shfl_xor(s, 32);
    float hn = a*xn + s;
    if (ch == 0) h2_s[d*16 + m] = hn;       // out overlay (wave-excl col)
    if (has_next) {
      const float* wu = Wu_next + l*1024 + d;
      float u = 0.0f;
      #pragma unroll 4
      for (int cc = 0; cc < 16; ++cc) {
        int c2 = cc + ch*16;
        u += h2_s[c2*16 + m] * wu[c2*32];    // reads out (same wave wrote)
      }
      u += __shfl_xor(u, 32);
      if (ch == 0) al_s[d*16 + m] = u;      // hu overlay (wave-excl col)
    }
  }

  // readout (wave 0 reads its own out m=0 column)
  if (t < 64) {
    float pre = br1[t];
    #pragma unroll 4
    for (int cc = 0; cc < CC; ++cc) pre += h2_s[cc*16] * Wr1[cc*64 + t];
    float v = siluf(pre) * Wr2[t];
    #pragma unroll
    for (int off2 = 32; off2 > 0; off2 >>= 1) v += __shfl_down(v, off2);
    if (t == 0) node_e[n] += siluf(v);
  }
  __syncthreads();   // out/hu complete

  h[(size_t)n*512 + t]       = h2_s[t];
  h[(size_t)n*512 + t + 256] = h2_s[t + 256];
  if (has_next) {
    hu_out[(size_t)n*512 + t]       = al_s[t];
    hu_out[(size_t)n*512 + t + 256] = al_s[t + 256];
  }
}

// ---------------------------------------------------------------------------
// Kernel 7: per-graph sum of node energies
// ---------------------------------------------------------------------------
__global__ __launch_bounds__(128) void k_out(
    const float* __restrict__ node_e, float* __restrict__ out)
{
  int g = blockIdx.x, t = threadIdx.x;
  float v = (t < NPG) ? node_e[g*NPG + t] : 0.0f;
  #pragma unroll
  for (int off2 = 32; off2 > 0; off2 >>= 1) v += __shfl_down(v, off2);
  __shared__ float r2[2];
  if ((t & 63) == 0) r2[t >> 6] = v;
  __syncthreads();
  if (t == 0) out[g] = r2[0] + r2[1];
}

// Diagnostic: if workspace too small, report its size (MB) via absmax
__global__ void k_dbg(float* __restrict__ out, float v) {
  int i = blockIdx.x * 64 + threadIdx.x;
  if (i < GG) out[i] = v;
}

// ---------------------------------------------------------------------------
extern "C" void kernel_launch(void* const* d_in, const int* in_sizes, int n_in,
                              void* d_out, int out_size, void* d_ws, size_t ws_size,
                              hipStream_t stream)
{
  const float* positions = (const float*)d_in[0];
  const float* cell      = (const float*)d_in[1];
  const int*   Sij       = (const int*)d_in[2];
  const int*   eidx      = (const int*)d_in[3];
  const int*   species   = (const int*)d_in[4];
  const int*   batch     = (const int*)d_in[5];
  const float* W_emb     = (const float*)d_in[6];
  const float* W_xtp     = (const float*)d_in[7];
  const float* W_up      = (const float*)d_in[8];
  const float* W1        = (const float*)d_in[9];
  const float* b1        = (const float*)d_in[10];
  const float* W2        = (const float*)d_in[11];
  const float* b2        = (const float*)d_in[12];
  const float* W3        = (const float*)d_in[13];
  const float* W_down    = (const float*)d_in[14];
  const float* W_sc      = (const float*)d_in[15];
  const float* Wr1       = (const float*)d_in[16];
  const float* br1       = (const float*)d_in[17];
  const float* Wr2       = (const float*)d_in[18];
  float* out = (float*)d_out;
  (void)in_sizes; (void)n_in; (void)out_size;

  const size_t NEED = 149000000;  // proven available in R8
  if (ws_size < NEED) {
    k_dbg<<<dim3(2), dim3(64), 0, stream>>>(out, (float)(ws_size >> 20));
    return;
  }

  char* ws = (char*)d_ws;
  size_t off = 0;
  auto alloc = [&](size_t bytes) -> void* {
    void* p = ws + off;
    off += (bytes + 255) & ~(size_t)255;
    return p;
  };
  float*     Yb      = (float*)alloc((size_t)EE*16*4);   // 25.6 MB
  __half*    efb     = (__half*)alloc((size_t)EE*8*2);   //  6.4 MB
  float*     hb      = (float*)alloc((size_t)NN*512*4);  // 20.5 MB
  float*     huA     = (float*)alloc((size_t)NN*512*4);  // 20.5 MB
  float*     huB     = (float*)alloc((size_t)NN*512*4);  // 20.5 MB
  float*     xnodeb  = (float*)alloc((size_t)NN*4);
  float*     node_eb = (float*)alloc((size_t)NN*4);
  int*       offb    = (int*)alloc((size_t)(NN+1)*4);
  int*       curb    = (int*)alloc((size_t)NN*4);
  int2*      elistb  = (int2*)alloc((size_t)EE*8);       //  3.2 MB
  _Float16*  W2tb    = (_Float16*)alloc((size_t)NLAYER*64*64*2);
  _Float16*  W3tb    = (_Float16*)alloc((size_t)NLAYER*64*256*2);
  __half*    hm2b    = (__half*)alloc((size_t)EE*64*2);  // 51.2 MB

  dim3 blk(256);
  k_geom<<<dim3((EE + 255)/256), blk, 0, stream>>>(positions, cell, Sij, eidx, batch, Yb, efb);
  k_init<<<dim3((NN*CC + 255)/256), blk, 0, stream>>>(species, W_emb, W_xtp, hb, xnodeb, node_eb);
  k_wconv<<<dim3((NLAYER*64*256 + 255)/256), blk, 0, stream>>>(W2, W3, W2tb, W3tb);

  // CSR build (layer-invariant)
  k_csr_zero <<<dim3((NN + 255)/256), blk, 0, stream>>>(curb);
  k_csr_count<<<dim3((EE + 255)/256), blk, 0, stream>>>(eidx, curb);
  k_csr_scan <<<dim3(GG), dim3(128), 0, stream>>>(curb, offb, curb);
  k_csr_fill <<<dim3((EE + 255)/256), blk, 0, stream>>>(eidx, curb, elistb);

  // layer 0 hu from initial h
  k_hu<<<dim3(NN), blk, 0, stream>>>(hb, W_up + 0*4096, huA);

  float* hin = huA; float* hout = huB;
  for (int layer = 0; layer < NLAYER; ++layer) {
    int has_next = (layer + 1 < NLAYER) ? 1 : 0;
    k_mlp<<<dim3(6256), blk, 0, stream>>>(efb,
        W1 + layer*NBES*64, b1 + layer*64,
        W2tb + layer*4096, b2 + layer*64, hm2b);
    k_gather<<<dim3(NN), blk, 0, stream>>>(elistb, offb, Yb, hm2b,
        W3tb + layer*16384, hin,
        species, xnodeb,
        W_down + layer*4096, W_sc + layer*16384,
        Wr1 + layer*CC*64, br1 + layer*64, Wr2 + layer*64, node_eb,
        W_up + (has_next ? (layer+1)*4096 : 0), hout, hb, has_next);
    float* tmp = hin; hin = hout; hout = tmp;
  }
  k_out<<<dim3(GG), dim3(128), 0, stream>>>(node_eb, out);
}

// Round 12
// 1071.275 us; speedup vs baseline: 1.4001x; 1.1006x over previous
//
#include <hip/hip_runtime.h>
#include <hip/hip_bf16.h>
#include <hip/hip_fp16.h>
#include <stdint.h>

// Problem constants (match reference)
#define NN   10000
#define GG   100
#define NPG  100
#define EE   400000
#define EPG  4000
#define CC   32
#define LM   16
#define SS   4
#define NBES 8
#define NLAYER 3
#define INV_AVG (1.0f/40.0f)

typedef _Float16 f16x8 __attribute__((ext_vector_type(8)));
typedef _Float16 f16x4 __attribute__((ext_vector_type(4)));
typedef _Float16 f16x2 __attribute__((ext_vector_type(2)));
typedef float    f32x4 __attribute__((ext_vector_type(4)));

__device__ __forceinline__ float siluf(float x) { return x / (1.0f + __expf(-x)); }
__device__ __forceinline__ int lof(int m) { return (m >= 1) + (m >= 4) + (m >= 9); }

// ---------------------------------------------------------------------------
// Kernel 1: per-edge geometry -> Y[E,16] f16, ef[E,8] f16  (layer-invariant)
// ---------------------------------------------------------------------------
__global__ __launch_bounds__(256) void k_geom(
    const float* __restrict__ pos, const float* __restrict__ cell,
    const int* __restrict__ Sij, const int* __restrict__ eidx,
    const int* __restrict__ batch, __half* __restrict__ Y, __half* __restrict__ ef)
{
  int e = blockIdx.x * 256 + threadIdx.x;
  if (e >= EE) return;
  int ia = eidx[e], ja = eidx[EE + e];
  int g = batch[ia];
  float s0 = (float)Sij[e*3+0], s1 = (float)Sij[e*3+1], s2 = (float)Sij[e*3+2];
  const float* cg = cell + g*9;
  float shx = s0*cg[0] + s1*cg[3] + s2*cg[6];
  float shy = s0*cg[1] + s1*cg[4] + s2*cg[7];
  float shz = s0*cg[2] + s1*cg[5] + s2*cg[8];
  float rx = (pos[ja*3+0] - pos[ia*3+0] + shx) / 6.0f;
  float ry = (pos[ja*3+1] - pos[ia*3+1] + shy) / 6.0f;
  float rz = (pos[ja*3+2] - pos[ia*3+2] + shz) / 6.0f;
  float r2 = rx*rx + ry*ry + rz*rz;
  float r  = sqrtf(r2);
  float rs = (r > 1e-9f) ? r : 1e-9f;
  float inv = 1.0f / rs;
  float x = rx*inv, y = ry*inv, z = rz*inv;

  const float s3   = 1.7320508075688772f;
  const float s15  = 3.872983346207417f;
  const float s5h  = 1.118033988749895f;
  const float s15h = 1.9364916731037085f;
  const float s358 = 2.091650066335189f;
  const float s105 = 10.246950765959598f;
  const float s218 = 1.620185174601965f;
  const float s7h  = 1.3228756555322954f;
  const float s105h= 5.123475382979799f;

  float xx = x*x, yy = y*y, zz = z*z;
  float yv[16];
  yv[0]  = 1.0f;
  yv[1]  = s3*x;  yv[2] = s3*y;  yv[3] = s3*z;
  yv[4]  = s15*x*y; yv[5] = s15*y*z; yv[6] = s5h*(3.0f*zz - 1.0f);
  yv[7]  = s15*x*z; yv[8] = s15h*(xx - yy);
  yv[9]  = s358*y*(3.0f*xx - yy);
  yv[10] = s105*x*y*z;
  yv[11] = s218*y*(5.0f*zz - 1.0f);
  yv[12] = s7h*(5.0f*zz*z - 3.0f*z);
  yv[13] = s218*x*(5.0f*zz - 1.0f);
  yv[14] = s105h*z*(xx - yy);
  yv[15] = s358*x*(xx - 3.0f*yy);

  union { __half h[16]; uint4 u[2]; } yp;
  #pragma unroll
  for (int i = 0; i < 16; ++i) yp.h[i] = __float2half(yv[i]);
  uint4* Yp = (uint4*)(Y + (size_t)e*16);
  Yp[0] = yp.u[0];
  Yp[1] = yp.u[1];

  float f = 0.0f;
  if (r < 1.0f) f = 1.0f - 6.0f*r2 + 8.0f*r2*r - 3.0f*r2*r2;
  float c1 = 1.4142135623730951f * f * inv;
  float ang = 3.14159265358979323846f * rs;
  float sn = __sinf(ang), cn = __cosf(ang);
  float twoc = 2.0f * cn;
  float sprev = 0.0f, scur = sn;
  union { __half h[8]; uint4 u; } p;
  #pragma unroll
  for (int n1 = 1; n1 <= NBES; ++n1) {
    p.h[n1-1] = __float2half(c1 * scur);
    float snext = twoc * scur - sprev;
    sprev = scur; scur = snext;
  }
  *(uint4*)(ef + (size_t)e*8) = p.u;
}

// ---------------------------------------------------------------------------
// CSR build (layer-invariant)
// ---------------------------------------------------------------------------
__global__ __launch_bounds__(256) void k_csr_zero(int* __restrict__ cnt) {
  int n = blockIdx.x * 256 + threadIdx.x;
  if (n < NN) cnt[n] = 0;
}

__global__ __launch_bounds__(256) void k_csr_count(
    const int* __restrict__ eidx, int* __restrict__ cnt) {
  int e = blockIdx.x * 256 + threadIdx.x;
  if (e < EE) atomicAdd(&cnt[eidx[e]], 1);
}

__global__ __launch_bounds__(128) void k_csr_scan(
    const int* __restrict__ cnt, int* __restrict__ off, int* __restrict__ cursor) {
  __shared__ int s[128];
  int g = blockIdx.x, t = threadIdx.x;
  int own = (t < NPG) ? cnt[g*NPG + t] : 0;
  s[t] = own;
  __syncthreads();
  #pragma unroll
  for (int d = 1; d < 128; d <<= 1) {
    int v = (t >= d) ? s[t-d] : 0;
    __syncthreads();
    s[t] += v;
    __syncthreads();
  }
  if (t < NPG) {
    int o = g*EPG + s[t] - own;
    off[g*NPG + t] = o;
    cursor[g*NPG + t] = o;
    if (g == GG-1 && t == NPG-1) off[NN] = EE;
  }
}

__global__ __launch_bounds__(256) void k_csr_fill(
    const int* __restrict__ eidx, int* __restrict__ cursor, int2* __restrict__ elist) {
  int e = blockIdx.x * 256 + threadIdx.x;
  if (e >= EE) return;
  int ia = eidx[e], ja = eidx[EE + e];
  int pos = atomicAdd(&cursor[ia], 1);
  elist[pos] = make_int2(e, ja);
}

// ---------------------------------------------------------------------------
// Weight conversion (once per call): W2t[l][j][k], W3t[l][j][k] fp16
// ---------------------------------------------------------------------------
__global__ __launch_bounds__(256) void k_wconv(
    const float* __restrict__ W2, const float* __restrict__ W3,
    _Float16* __restrict__ W2t, _Float16* __restrict__ W3t)
{
  int idx = blockIdx.x * 256 + threadIdx.x;
  if (idx < NLAYER*64*64) {
    int l = idx / 4096, rem = idx % 4096, k = rem / 64, j = rem % 64;
    W2t[l*4096 + j*64 + k] = (_Float16)W2[idx];
  }
  if (idx < NLAYER*64*256) {
    int l = idx / 16384, rem = idx % 16384, k = rem / 256, j = rem % 256;
    W3t[l*16384 + j*64 + k] = (_Float16)W3[idx];
  }
}

// ---------------------------------------------------------------------------
// Kernel 2: node init
// ---------------------------------------------------------------------------
__global__ __launch_bounds__(256) void k_init(
    const int* __restrict__ species, const float* __restrict__ W_emb,
    const float* __restrict__ W_xtp, float* __restrict__ h,
    float* __restrict__ xnode, float* __restrict__ node_e)
{
  int idx = blockIdx.x * 256 + threadIdx.x;
  if (idx >= NN*CC) return;
  int n = idx / CC, c = idx % CC;
  int sp = species[n];
  float h0 = W_emb[sp*CC + c];
  float* hp = h + (size_t)n*512 + c*16;
  hp[0] = h0;
  #pragma unroll
  for (int m = 1; m < 16; ++m) hp[m] = 0.0f;
  if (c == 0) {
    float xn = 0.0f;
    for (int c2 = 0; c2 < CC; ++c2) xn += W_emb[sp*CC + c2] * W_xtp[c2*SS + sp];
    xnode[n] = xn;
    node_e[n] = 0.0f;
  }
}

// ---------------------------------------------------------------------------
// Kernel 3 (layer 0 only): hu = h @ Wu (fp16 out), coalesced weight access
// ---------------------------------------------------------------------------
__global__ __launch_bounds__(256) void k_hu(
    const float* __restrict__ h, const float* __restrict__ Wu,
    __half* __restrict__ hu)
{
  __shared__ float h_s[512];
  __shared__ float hu_s[512];
  int n = blockIdx.x, t = threadIdx.x;
  h_s[t]       = h[(size_t)n*512 + t];
  h_s[t + 256] = h[(size_t)n*512 + t + 256];
  __syncthreads();
  int lane = t & 63, wv = t >> 6;
  int d = lane & 31, ch = lane >> 5;
  #pragma unroll
  for (int mi = 0; mi < 4; ++mi) {
    int m = wv*4 + mi;
    int l = lof(m);
    const float* wu = Wu + l*1024 + d;
    float u = 0.0f;
    #pragma unroll 4
    for (int cc = 0; cc < 16; ++cc) {
      int c = cc + ch*16;
      u += h_s[c*16 + m] * wu[c*32];
    }
    u += __shfl_xor(u, 32);
    if (ch == 0) hu_s[d*16 + m] = u;
  }
  __syncthreads();
  __half2 o;
  o.x = __float2half(hu_s[2*t]);
  o.y = __float2half(hu_s[2*t + 1]);
  *(__half2*)(hu + (size_t)n*512 + 2*t) = o;
}

// ---------------------------------------------------------------------------
// Kernel 4 (per layer): edge MLP, edge-major streaming:
// ef(8) -> hm1(64) fp32 VALU -> hm2(64) MFMA, silu, fp16 global.
// ---------------------------------------------------------------------------
__global__ __launch_bounds__(256) void k_mlp(
    const __half* __restrict__ ef, const float* __restrict__ W1,
    const float* __restrict__ b1, const _Float16* __restrict__ W2t,
    const float* __restrict__ b2, __half* __restrict__ hm2)
{
  __shared__ _Float16 hm1_s[4][16*72];
  int b = blockIdx.x, t = threadIdx.x;
  int eb = (b & 7) * 782 + (b >> 3);
  if (eb >= EE/64) return;
  int wv = t >> 6, lane = t & 63;
  int ln15 = lane & 15, quad = lane >> 4;
  _Float16* hm1 = hm1_s[wv];
  size_t e16 = (size_t)eb*64 + wv*16;

  union { uint4 u; __half hh[8]; } efv;
  efv.u = *(const uint4*)(ef + (e16 + ln15)*8);
  float ev[8];
  #pragma unroll
  for (int k = 0; k < 8; ++k) ev[k] = __half2float(efv.hh[k]);
  #pragma unroll
  for (int p = 0; p < 4; ++p) {
    int j0 = p*16 + quad*4;
    float4 a = *(const float4*)(b1 + j0);
    #pragma unroll
    for (int k = 0; k < 8; ++k) {
      const float4 w = *(const float4*)(W1 + k*64 + j0);
      a.x += ev[k]*w.x; a.y += ev[k]*w.y; a.z += ev[k]*w.z; a.w += ev[k]*w.w;
    }
    f16x4 pk;
    pk[0] = (_Float16)siluf(a.x);
    pk[1] = (_Float16)siluf(a.y);
    pk[2] = (_Float16)siluf(a.z);
    pk[3] = (_Float16)siluf(a.w);
    *(f16x4*)&hm1[ln15*72 + j0] = pk;
  }

  f16x8 a0 = *(const f16x8*)(hm1 + ln15*72 + quad*8);
  f16x8 a1 = *(const f16x8*)(hm1 + ln15*72 + 32 + quad*8);
  #pragma unroll
  for (int cg = 0; cg < 4; ++cg) {
    int col = cg*16 + ln15;
    f32x4 d = {0.f, 0.f, 0.f, 0.f};
    d = __builtin_amdgcn_mfma_f32_16x16x32_f16(a0, *(const f16x8*)(W2t + (size_t)col*64 + quad*8), d, 0, 0, 0);
    d = __builtin_amdgcn_mfma_f32_16x16x32_f16(a1, *(const f16x8*)(W2t + (size_t)col*64 + 32 + quad*8), d, 0, 0, 0);
    float bb = b2[col];
    #pragma unroll
    for (int r = 0; r < 4; ++r)
      hm2[(e16 + quad*4 + r)*64 + col] = __float2half(siluf(d[r] + bb));
  }
}

// ---------------------------------------------------------------------------
// Kernel 5 (per layer): block-per-node gather, zero barriers in tile loop.
// fp16 hu/Y + packed half2 message math; edge list in per-wave LDS
// (ds_read_b64 instead of ds_bpermute); A-frags from global hm2, prefetched.
// ---------------------------------------------------------------------------
__global__ __launch_bounds__(256) void k_gather(
    const int2* __restrict__ elist, const int* __restrict__ off,
    const __half* __restrict__ Y, const __half* __restrict__ hm2,
    const _Float16* __restrict__ W3t, const __half* __restrict__ hu_in,
    const int* __restrict__ species, const float* __restrict__ xnode,
    const float* __restrict__ Wd, const float* __restrict__ Wsc,
    const float* __restrict__ Wr1, const float* __restrict__ br1,
    const float* __restrict__ Wr2, float* __restrict__ node_e,
    const float* __restrict__ Wu_next, __half* __restrict__ hu_out,
    float* __restrict__ h, int has_next)
{
  // rw slab: 4 waves x 32 rows x 68 halfs = 17408 B (+1KB elw).
  // Epilogue overlays al(2KB)+out/h2(2KB) on the front (barrier-guarded).
  __shared__ _Float16 rw_all[4][32*68];
  __shared__ int2 elw_s[4][32];
  float* al_s = (float*)&rw_all[0][0];
  float* h2_s = al_s + 512;

  int b = blockIdx.x, t = threadIdx.x;
  int n = (b & 7) * (NN/8) + (b >> 3);   // XCD-locality swizzle
  int beg = off[n], deg = off[n+1] - beg;

  int lane = t & 63, wv = t >> 6;
  int ln15 = lane & 15, quad = lane >> 4;
  _Float16* rww = rw_all[wv];
  int2* elw = elw_s[wv];
  const _Float16* hm2h = (const _Float16*)hm2;
  const _Float16* Yh = (const _Float16*)Y;
  const _Float16* huh = (const _Float16*)hu_in;

  // stage this node's h in registers (LDS busy until epilogue)
  float hreg0 = h[(size_t)n*512 + t];
  float hreg1 = h[(size_t)n*512 + t + 256];

  // message mapping (wave-local: c in [wv*8, wv*8+8))
  int cl = lane >> 3, m0 = (lane & 7) * 2;
  int c = wv*8 + cl, cl4 = cl*4;
  int cl8 = lane & 56;                   // lane holding m0=0 for this c
  int l0 = lof(m0), l1 = lof(m0 + 1);
  float acc0 = 0.0f, acc1 = 0.0f;

  // ---- prefetch tile 0: edge list (lanes 0..31) + A-frags from global hm2
  int2 el_cur = make_int2(0, 0);
  f16x8 aA0 = {}, aA1 = {}, aB0 = {}, aB1 = {};
  if (deg > 0) {
    int idx = lane < deg ? lane : deg - 1;
    el_cur = elist[beg + idx];
    int eA = __shfl(el_cur.x, ln15);
    int eB = __shfl(el_cur.x, 16 + ln15);
    aA0 = *(const f16x8*)(hm2h + (size_t)eA*64 + quad*8);
    aA1 = *(const f16x8*)(hm2h + (size_t)eA*64 + 32 + quad*8);
    aB0 = *(const f16x8*)(hm2h + (size_t)eB*64 + quad*8);
    aB1 = *(const f16x8*)(hm2h + (size_t)eB*64 + 32 + quad*8);
  }

  for (int base = 0; base < deg; base += 32) {
    int cnt = min(32, deg - base);
    if (lane < 32) elw[lane] = el_cur;   // publish for message loop (same wave)

    // ---- GEMM3: 16 MFMA, wave-local columns; rows 0-15 (A), 16-31 (B)
    #pragma unroll
    for (int cg = 0; cg < 4; ++cg) {
      int colg = (cg < 2) ? (wv*32 + cg*16 + ln15)
                          : (128 + wv*32 + (cg-2)*16 + ln15);
      f16x8 b0 = *(const f16x8*)(W3t + (size_t)colg*64 + quad*8);
      f16x8 b1v = *(const f16x8*)(W3t + (size_t)colg*64 + 32 + quad*8);
      f32x4 dA = {0.f, 0.f, 0.f, 0.f};
      dA = __builtin_amdgcn_mfma_f32_16x16x32_f16(aA0, b0, dA, 0, 0, 0);
      dA = __builtin_amdgcn_mfma_f32_16x16x32_f16(aA1, b1v, dA, 0, 0, 0);
      f32x4 dB = {0.f, 0.f, 0.f, 0.f};
      dB = __builtin_amdgcn_mfma_f32_16x16x32_f16(aB0, b0, dB, 0, 0, 0);
      dB = __builtin_amdgcn_mfma_f32_16x16x32_f16(aB1, b1v, dB, 0, 0, 0);
      #pragma unroll
      for (int r = 0; r < 4; ++r) {
        rww[(quad*4 + r)*68 + cg*16 + ln15]      = (_Float16)dA[r];
        rww[(16 + quad*4 + r)*68 + cg*16 + ln15] = (_Float16)dB[r];
      }
    }

    // ---- prefetch next tile (elist + A-frags), overlaps message loop
    int2 el_nxt = el_cur;
    f16x8 nA0 = aA0, nA1 = aA1, nB0 = aB0, nB1 = aB1;
    if (base + 32 < deg) {
      int idx = base + 32 + lane;
      if (idx >= deg) idx = deg - 1;
      el_nxt = elist[beg + idx];
      int eA = __shfl(el_nxt.x, ln15);
      int eB = __shfl(el_nxt.x, 16 + ln15);
      nA0 = *(const f16x8*)(hm2h + (size_t)eA*64 + quad*8);
      nA1 = *(const f16x8*)(hm2h + (size_t)eA*64 + 32 + quad*8);
      nB0 = *(const f16x8*)(hm2h + (size_t)eB*64 + quad*8);
      nB1 = *(const f16x8*)(hm2h + (size_t)eB*64 + 32 + quad*8);
    }

    // ---- message accumulate (packed fp16, per-tile fp16 accumulator)
    f16x2 accv = {(_Float16)0.f, (_Float16)0.f};
    #pragma unroll 8
    for (int i = 0; i < cnt; ++i) {
      int2 ed = elw[i];                               // ds_read_b64
      f16x2 hjm = *(const f16x2*)(huh + (size_t)ed.y*512 + c*16 + m0);
      int hj_i = __shfl(*(int*)&hjm, cl8);            // m0=0 lane of this c
      f16x2 hjv = *(f16x2*)&hj_i;
      f16x2 hj0v; hj0v[0] = hjv[0]; hj0v[1] = hjv[0];
      f16x2 Ym = *(const f16x2*)(Yh + (size_t)ed.x*16 + m0);
      f16x2 w0v; w0v[0] = rww[i*68 + cl4 + l0];      w0v[1] = rww[i*68 + cl4 + l1];
      f16x2 w1v; w1v[0] = rww[i*68 + 32 + cl4 + l0]; w1v[1] = rww[i*68 + 32 + cl4 + l1];
      accv += w0v * (Ym * hj0v) + w1v * hjm;
    }
    acc0 += (float)accv[0];
    acc1 += (float)accv[1];

    el_cur = el_nxt;
    aA0 = nA0; aA1 = nA1; aB0 = nB0; aB1 = nB1;
  }

  __syncthreads();   // tile phase done -> overlay safe

  // ---- agg + h into phase2 LDS
  al_s[c*16 + m0]     = acc0 * INV_AVG;
  al_s[c*16 + m0 + 1] = acc1 * INV_AVG;
  h2_s[t]       = hreg0;
  h2_s[t + 256] = hreg1;
  __syncthreads();

  // ---- update epilogue (coalesced weights, wave-uniform l)
  int sp = species[n];
  float xn = xnode[n];
  int d = lane & 31, ch = lane >> 5;
  #pragma unroll
  for (int mi = 0; mi < 4; ++mi) {
    int m = wv*4 + mi;
    int l = lof(m);
    const float* wd  = Wd  + l*1024 + d;
    const float* wsc = Wsc + l*4096 + sp*32 + d;
    float a = 0.0f, s = 0.0f;
    #pragma unroll 4
    for (int cc = 0; cc < 16; ++cc) {
      int c2 = cc + ch*16;
      a += al_s[c2*16 + m] * wd[c2*32];
      s += h2_s[c2*16 + m] * wsc[c2*128];
    }
    a += __shfl_xor(a, 32);
    s += __shfl_xor(s, 32);
    float hn = a*xn + s;
    if (ch == 0) h2_s[d*16 + m] = hn;       // out overlay (wave-excl col)
    if (has_next) {
      const float* wu = Wu_next + l*1024 + d;
      float u = 0.0f;
      #pragma unroll 4
      for (int cc = 0; cc < 16; ++cc) {
        int c2 = cc + ch*16;
        u += h2_s[c2*16 + m] * wu[c2*32];    // reads out (same wave wrote)
      }
      u += __shfl_xor(u, 32);
      if (ch == 0) al_s[d*16 + m] = u;      // hu overlay (wave-excl col)
    }
  }

  // readout (wave 0 reads its own out m=0 column)
  if (t < 64) {
    float pre = br1[t];
    #pragma unroll 4
    for (int cc = 0; cc < CC; ++cc) pre += h2_s[cc*16] * Wr1[cc*64 + t];
    float v = siluf(pre) * Wr2[t];
    #pragma unroll
    for (int off2 = 32; off2 > 0; off2 >>= 1) v += __shfl_down(v, off2);
    if (t == 0) node_e[n] += siluf(v);
  }
  __syncthreads();   // out/hu complete

  h[(size_t)n*512 + t]       = h2_s[t];
  h[(size_t)n*512 + t + 256] = h2_s[t + 256];
  if (has_next) {
    __half2 o;
    o.x = __float2half(al_s[2*t]);
    o.y = __float2half(al_s[2*t + 1]);
    *(__half2*)(hu_out + (size_t)n*512 + 2*t) = o;
  }
}

// ---------------------------------------------------------------------------
// Kernel 7: per-graph sum of node energies
// ---------------------------------------------------------------------------
__global__ __launch_bounds__(128) void k_out(
    const float* __restrict__ node_e, float* __restrict__ out)
{
  int g = blockIdx.x, t = threadIdx.x;
  float v = (t < NPG) ? node_e[g*NPG + t] : 0.0f;
  #pragma unroll
  for (int off2 = 32; off2 > 0; off2 >>= 1) v += __shfl_down(v, off2);
  __shared__ float r2[2];
  if ((t & 63) == 0) r2[t >> 6] = v;
  __syncthreads();
  if (t == 0) out[g] = r2[0] + r2[1];
}

// Diagnostic: if workspace too small, report its size (MB) via absmax
__global__ void k_dbg(float* __restrict__ out, float v) {
  int i = blockIdx.x * 64 + threadIdx.x;
  if (i < GG) out[i] = v;
}

// ---------------------------------------------------------------------------
extern "C" void kernel_launch(void* const* d_in, const int* in_sizes, int n_in,
                              void* d_out, int out_size, void* d_ws, size_t ws_size,
                              hipStream_t stream)
{
  const float* positions = (const float*)d_in[0];
  const float* cell      = (const float*)d_in[1];
  const int*   Sij       = (const int*)d_in[2];
  const int*   eidx      = (const int*)d_in[3];
  const int*   species   = (const int*)d_in[4];
  const int*   batch     = (const int*)d_in[5];
  const float* W_emb     = (const float*)d_in[6];
  const float* W_xtp     = (const float*)d_in[7];
  const float* W_up      = (const float*)d_in[8];
  const float* W1        = (const float*)d_in[9];
  const float* b1        = (const float*)d_in[10];
  const float* W2        = (const float*)d_in[11];
  const float* b2        = (const float*)d_in[12];
  const float* W3        = (const float*)d_in[13];
  const float* W_down    = (const float*)d_in[14];
  const float* W_sc      = (const float*)d_in[15];
  const float* Wr1       = (const float*)d_in[16];
  const float* br1       = (const float*)d_in[17];
  const float* Wr2       = (const float*)d_in[18];
  float* out = (float*)d_out;
  (void)in_sizes; (void)n_in; (void)out_size;

  const size_t NEED = 120000000;  // ~117 MB actual
  if (ws_size < NEED) {
    k_dbg<<<dim3(2), dim3(64), 0, stream>>>(out, (float)(ws_size >> 20));
    return;
  }

  char* ws = (char*)d_ws;
  size_t off = 0;
  auto alloc = [&](size_t bytes) -> void* {
    void* p = ws + off;
    off += (bytes + 255) & ~(size_t)255;
    return p;
  };
  __half*    Yb      = (__half*)alloc((size_t)EE*16*2);  // 12.8 MB
  __half*    efb     = (__half*)alloc((size_t)EE*8*2);   //  6.4 MB
  float*     hb      = (float*)alloc((size_t)NN*512*4);  // 20.5 MB
  __half*    huA     = (__half*)alloc((size_t)NN*512*2); // 10.2 MB
  __half*    huB     = (__half*)alloc((size_t)NN*512*2); // 10.2 MB
  float*     xnodeb  = (float*)alloc((size_t)NN*4);
  float*     node_eb = (float*)alloc((size_t)NN*4);
  int*       offb    = (int*)alloc((size_t)(NN+1)*4);
  int*       curb    = (int*)alloc((size_t)NN*4);
  int2*      elistb  = (int2*)alloc((size_t)EE*8);       //  3.2 MB
  _Float16*  W2tb    = (_Float16*)alloc((size_t)NLAYER*64*64*2);
  _Float16*  W3tb    = (_Float16*)alloc((size_t)NLAYER*64*256*2);
  __half*    hm2b    = (__half*)alloc((size_t)EE*64*2);  // 51.2 MB

  dim3 blk(256);
  k_geom<<<dim3((EE + 255)/256), blk, 0, stream>>>(positions, cell, Sij, eidx, batch, Yb, efb);
  k_init<<<dim3((NN*CC + 255)/256), blk, 0, stream>>>(species, W_emb, W_xtp, hb, xnodeb, node_eb);
  k_wconv<<<dim3((NLAYER*64*256 + 255)/256), blk, 0, stream>>>(W2, W3, W2tb, W3tb);

  // CSR build (layer-invariant)
  k_csr_zero <<<dim3((NN + 255)/256), blk, 0, stream>>>(curb);
  k_csr_count<<<dim3((EE + 255)/256), blk, 0, stream>>>(eidx, curb);
  k_csr_scan <<<dim3(GG), dim3(128), 0, stream>>>(curb, offb, curb);
  k_csr_fill <<<dim3((EE + 255)/256), blk, 0, stream>>>(eidx, curb, elistb);

  // layer 0 hu from initial h
  k_hu<<<dim3(NN), blk, 0, stream>>>(hb, W_up + 0*4096, huA);

  __half* hin = huA; __half* hout = huB;
  for (int layer = 0; layer < NLAYER; ++layer) {
    int has_next = (layer + 1 < NLAYER) ? 1 : 0;
    k_mlp<<<dim3(6256), blk, 0, stream>>>(efb,
        W1 + layer*NBES*64, b1 + layer*64,
        W2tb + layer*4096, b2 + layer*64, hm2b);
    k_gather<<<dim3(NN), blk, 0, stream>>>(elistb, offb, Yb, hm2b,
        W3tb + layer*16384, hin,
        species, xnodeb,
        W_down + layer*4096, W_sc + layer*16384,
        Wr1 + layer*CC*64, br1 + layer*64, Wr2 + layer*64, node_eb,
        W_up + (has_next ? (layer+1)*4096 : 0), hout, hb, has_next);
    __half* tmp = hin; hin = hout; hout = tmp;
  }
  k_out<<<dim3(GG), dim3(128), 0, stream>>>(node_eb, out);
}

// Round 13
// 1052.878 us; speedup vs baseline: 1.4246x; 1.0175x over previous
//
#include <hip/hip_runtime.h>
#include <hip/hip_bf16.h>
#include <hip/hip_fp16.h>
#include <stdint.h>

// Problem constants (match reference)
#define NN   10000
#define GG   100
#define NPG  100
#define EE   400000
#define EPG  4000
#define CC   32
#define LM   16
#define SS   4
#define NBES 8
#define NLAYER 3
#define INV_AVG (1.0f/40.0f)
#define MLPB 6256   // mlp block count (8*782 >= EE/64)

typedef _Float16 f16x8 __attribute__((ext_vector_type(8)));
typedef _Float16 f16x4 __attribute__((ext_vector_type(4)));
typedef _Float16 f16x2 __attribute__((ext_vector_type(2)));
typedef float    f32x4 __attribute__((ext_vector_type(4)));

__device__ __forceinline__ float siluf(float x) { return x / (1.0f + __expf(-x)); }
__device__ __forceinline__ int lof(int m) { return (m >= 1) + (m >= 4) + (m >= 9); }

// ---------------------------------------------------------------------------
// geometry body (per edge): Y[E,16] f16, ef[E,8] f16
// ---------------------------------------------------------------------------
__device__ __forceinline__ void geom_body(
    int e, const float* __restrict__ pos, const float* __restrict__ cell,
    const int* __restrict__ Sij, const int* __restrict__ eidx,
    const int* __restrict__ batch, __half* __restrict__ Y, __half* __restrict__ ef)
{
  int ia = eidx[e], ja = eidx[EE + e];
  int g = batch[ia];
  float s0 = (float)Sij[e*3+0], s1 = (float)Sij[e*3+1], s2 = (float)Sij[e*3+2];
  const float* cg = cell + g*9;
  float shx = s0*cg[0] + s1*cg[3] + s2*cg[6];
  float shy = s0*cg[1] + s1*cg[4] + s2*cg[7];
  float shz = s0*cg[2] + s1*cg[5] + s2*cg[8];
  float rx = (pos[ja*3+0] - pos[ia*3+0] + shx) / 6.0f;
  float ry = (pos[ja*3+1] - pos[ia*3+1] + shy) / 6.0f;
  float rz = (pos[ja*3+2] - pos[ia*3+2] + shz) / 6.0f;
  float r2 = rx*rx + ry*ry + rz*rz;
  float r  = sqrtf(r2);
  float rs = (r > 1e-9f) ? r : 1e-9f;
  float inv = 1.0f / rs;
  float x = rx*inv, y = ry*inv, z = rz*inv;

  const float s3   = 1.7320508075688772f;
  const float s15  = 3.872983346207417f;
  const float s5h  = 1.118033988749895f;
  const float s15h = 1.9364916731037085f;
  const float s358 = 2.091650066335189f;
  const float s105 = 10.246950765959598f;
  const float s218 = 1.620185174601965f;
  const float s7h  = 1.3228756555322954f;
  const float s105h= 5.123475382979799f;

  float xx = x*x, yy = y*y, zz = z*z;
  float yv[16];
  yv[0]  = 1.0f;
  yv[1]  = s3*x;  yv[2] = s3*y;  yv[3] = s3*z;
  yv[4]  = s15*x*y; yv[5] = s15*y*z; yv[6] = s5h*(3.0f*zz - 1.0f);
  yv[7]  = s15*x*z; yv[8] = s15h*(xx - yy);
  yv[9]  = s358*y*(3.0f*xx - yy);
  yv[10] = s105*x*y*z;
  yv[11] = s218*y*(5.0f*zz - 1.0f);
  yv[12] = s7h*(5.0f*zz*z - 3.0f*z);
  yv[13] = s218*x*(5.0f*zz - 1.0f);
  yv[14] = s105h*z*(xx - yy);
  yv[15] = s358*x*(xx - 3.0f*yy);

  union { __half h[16]; uint4 u[2]; } yp;
  #pragma unroll
  for (int i = 0; i < 16; ++i) yp.h[i] = __float2half(yv[i]);
  uint4* Yp = (uint4*)(Y + (size_t)e*16);
  Yp[0] = yp.u[0];
  Yp[1] = yp.u[1];

  float f = 0.0f;
  if (r < 1.0f) f = 1.0f - 6.0f*r2 + 8.0f*r2*r - 3.0f*r2*r2;
  float c1 = 1.4142135623730951f * f * inv;
  float ang = 3.14159265358979323846f * rs;
  float sn = __sinf(ang), cn = __cosf(ang);
  float twoc = 2.0f * cn;
  float sprev = 0.0f, scur = sn;
  union { __half h[8]; uint4 u; } p;
  #pragma unroll
  for (int n1 = 1; n1 <= NBES; ++n1) {
    p.h[n1-1] = __float2half(c1 * scur);
    float snext = twoc * scur - sprev;
    sprev = scur; scur = snext;
  }
  *(uint4*)(ef + (size_t)e*8) = p.u;
}

// ---------------------------------------------------------------------------
// k_pre: geom (1563) | init (1250) | wconv (192) | csr_count (1563)
// ---------------------------------------------------------------------------
__global__ __launch_bounds__(256) void k_pre(
    const float* __restrict__ pos, const float* __restrict__ cell,
    const int* __restrict__ Sij, const int* __restrict__ eidx,
    const int* __restrict__ batch, __half* __restrict__ Y, __half* __restrict__ ef,
    const int* __restrict__ species, const float* __restrict__ W_emb,
    const float* __restrict__ W_xtp, float* __restrict__ h,
    float* __restrict__ xnode, float* __restrict__ node_e,
    const float* __restrict__ W2, const float* __restrict__ W3,
    _Float16* __restrict__ W2t, _Float16* __restrict__ W3t,
    int* __restrict__ cnt)
{
  int b = blockIdx.x, t = threadIdx.x;
  if (b < 1563) {
    int e = b*256 + t;
    if (e < EE) geom_body(e, pos, cell, Sij, eidx, batch, Y, ef);
  } else if (b < 2813) {
    int idx = (b - 1563)*256 + t;
    if (idx < NN*CC) {
      int n = idx / CC, c = idx % CC;
      int sp = species[n];
      float h0 = W_emb[sp*CC + c];
      float* hp = h + (size_t)n*512 + c*16;
      hp[0] = h0;
      #pragma unroll
      for (int m = 1; m < 16; ++m) hp[m] = 0.0f;
      if (c == 0) {
        float xn = 0.0f;
        for (int c2 = 0; c2 < CC; ++c2) xn += W_emb[sp*CC + c2] * W_xtp[c2*SS + sp];
        xnode[n] = xn;
        node_e[n] = 0.0f;
      }
    }
  } else if (b < 3005) {
    int idx = (b - 2813)*256 + t;
    if (idx < NLAYER*64*64) {
      int l = idx / 4096, rem = idx % 4096, k = rem / 64, j = rem % 64;
      W2t[l*4096 + j*64 + k] = (_Float16)W2[idx];
    }
    if (idx < NLAYER*64*256) {
      int l = idx / 16384, rem = idx % 16384, k = rem / 256, j = rem % 256;
      W3t[l*16384 + j*64 + k] = (_Float16)W3[idx];
    }
  } else {
    int e = (b - 3005)*256 + t;
    if (e < EE) atomicAdd(&cnt[eidx[e]], 1);
  }
}

// ---------------------------------------------------------------------------
// CSR scan + fill
// ---------------------------------------------------------------------------
__global__ __launch_bounds__(128) void k_csr_scan(
    const int* __restrict__ cnt, int* __restrict__ off, int* __restrict__ cursor) {
  __shared__ int s[128];
  int g = blockIdx.x, t = threadIdx.x;
  int own = (t < NPG) ? cnt[g*NPG + t] : 0;
  s[t] = own;
  __syncthreads();
  #pragma unroll
  for (int d = 1; d < 128; d <<= 1) {
    int v = (t >= d) ? s[t-d] : 0;
    __syncthreads();
    s[t] += v;
    __syncthreads();
  }
  if (t < NPG) {
    int o = g*EPG + s[t] - own;
    off[g*NPG + t] = o;
    cursor[g*NPG + t] = o;
    if (g == GG-1 && t == NPG-1) off[NN] = EE;
  }
}

__global__ __launch_bounds__(256) void k_csr_fill(
    const int* __restrict__ eidx, int* __restrict__ cursor, int2* __restrict__ elist) {
  int e = blockIdx.x * 256 + threadIdx.x;
  if (e >= EE) return;
  int ia = eidx[e], ja = eidx[EE + e];
  int pos = atomicAdd(&cursor[ia], 1);
  elist[pos] = make_int2(e, ja);
}

// ---------------------------------------------------------------------------
// mlp body (per block of 64 edges): ef(8)->hm1(64) VALU -> hm2(64) MFMA f16
// pool16 must have 4*16*72 halfs available. Wave-autonomous, no barriers.
// ---------------------------------------------------------------------------
__device__ __forceinline__ void mlp_body(
    int mb, int t, _Float16* pool16,
    const __half* __restrict__ ef, const float* __restrict__ W1,
    const float* __restrict__ b1, const _Float16* __restrict__ W2t,
    const float* __restrict__ b2, __half* __restrict__ hm2)
{
  int eb = (mb & 7) * 782 + (mb >> 3);
  if (eb >= EE/64) return;
  int wv = t >> 6, lane = t & 63;
  int ln15 = lane & 15, quad = lane >> 4;
  _Float16* hm1 = pool16 + wv*(16*72);
  size_t e16 = (size_t)eb*64 + wv*16;

  union { uint4 u; __half hh[8]; } efv;
  efv.u = *(const uint4*)(ef + (e16 + ln15)*8);
  float ev[8];
  #pragma unroll
  for (int k = 0; k < 8; ++k) ev[k] = __half2float(efv.hh[k]);
  #pragma unroll
  for (int p = 0; p < 4; ++p) {
    int j0 = p*16 + quad*4;
    float4 a = *(const float4*)(b1 + j0);
    #pragma unroll
    for (int k = 0; k < 8; ++k) {
      const float4 w = *(const float4*)(W1 + k*64 + j0);
      a.x += ev[k]*w.x; a.y += ev[k]*w.y; a.z += ev[k]*w.z; a.w += ev[k]*w.w;
    }
    f16x4 pk;
    pk[0] = (_Float16)siluf(a.x);
    pk[1] = (_Float16)siluf(a.y);
    pk[2] = (_Float16)siluf(a.z);
    pk[3] = (_Float16)siluf(a.w);
    *(f16x4*)&hm1[ln15*72 + j0] = pk;
  }

  f16x8 a0 = *(const f16x8*)(hm1 + ln15*72 + quad*8);
  f16x8 a1 = *(const f16x8*)(hm1 + ln15*72 + 32 + quad*8);
  #pragma unroll
  for (int cg = 0; cg < 4; ++cg) {
    int col = cg*16 + ln15;
    f32x4 d = {0.f, 0.f, 0.f, 0.f};
    d = __builtin_amdgcn_mfma_f32_16x16x32_f16(a0, *(const f16x8*)(W2t + (size_t)col*64 + quad*8), d, 0, 0, 0);
    d = __builtin_amdgcn_mfma_f32_16x16x32_f16(a1, *(const f16x8*)(W2t + (size_t)col*64 + 32 + quad*8), d, 0, 0, 0);
    float bb = b2[col];
    #pragma unroll
    for (int r = 0; r < 4; ++r)
      hm2[(e16 + quad*4 + r)*64 + col] = __float2half(siluf(d[r] + bb));
  }
}

// standalone mlp (fallback path)
__global__ __launch_bounds__(256) void k_mlp(
    const __half* __restrict__ ef, const float* __restrict__ W1,
    const float* __restrict__ b1, const _Float16* __restrict__ W2t,
    const float* __restrict__ b2, __half* __restrict__ hm2)
{
  __shared__ _Float16 pool16[4*16*72];
  mlp_body(blockIdx.x, threadIdx.x, pool16, ef, W1, b1, W2t, b2, hm2);
}

// ---------------------------------------------------------------------------
// k_humlp: blocks [0,MLPB) run layer-0 mlp; blocks [MLPB, MLPB+NN) run hu.
// ---------------------------------------------------------------------------
__global__ __launch_bounds__(256) void k_humlp(
    const float* __restrict__ h, const float* __restrict__ Wu,
    __half* __restrict__ hu,
    const __half* __restrict__ ef, const float* __restrict__ W1,
    const float* __restrict__ b1, const _Float16* __restrict__ W2t,
    const float* __restrict__ b2, __half* __restrict__ hm2)
{
  __shared__ float pool[1152];   // 4608 B for hu part; mlp uses it as halfs
  int b = blockIdx.x, t = threadIdx.x;
  if (b < MLPB) {
    __shared__ _Float16 pool16[4*16*72];
    mlp_body(b, t, pool16, ef, W1, b1, W2t, b2, hm2);
    return;
  }
  int n = b - MLPB;
  float* h_s = pool;
  float* hu_s = pool + 512;
  h_s[t]       = h[(size_t)n*512 + t];
  h_s[t + 256] = h[(size_t)n*512 + t + 256];
  __syncthreads();
  int lane = t & 63, wv = t >> 6;
  int d = lane & 31, ch = lane >> 5;
  #pragma unroll
  for (int mi = 0; mi < 4; ++mi) {
    int m = wv*4 + mi;
    int l = lof(m);
    const float* wu = Wu + l*1024 + d;
    float u = 0.0f;
    #pragma unroll 4
    for (int cc = 0; cc < 16; ++cc) {
      int c = cc + ch*16;
      u += h_s[c*16 + m] * wu[c*32];
    }
    u += __shfl_xor(u, 32);
    if (ch == 0) hu_s[d*16 + m] = u;
  }
  __syncthreads();
  __half2 o;
  o.x = __float2half(hu_s[2*t]);
  o.y = __float2half(hu_s[2*t + 1]);
  *(__half2*)(hu + (size_t)n*512 + 2*t) = o;
}

// ---------------------------------------------------------------------------
// k_gather: optional fused next-layer mlp blocks first (do_mlp), then
// block-per-node gather (R12 body + b32 w-select).
// ---------------------------------------------------------------------------
__global__ __launch_bounds__(256) void k_gather(
    const int2* __restrict__ elist, const int* __restrict__ off,
    const __half* __restrict__ Y, const __half* __restrict__ hm2,
    const _Float16* __restrict__ W3t, const __half* __restrict__ hu_in,
    const int* __restrict__ species, const float* __restrict__ xnode,
    const float* __restrict__ Wd, const float* __restrict__ Wsc,
    const float* __restrict__ Wr1, const float* __restrict__ br1,
    const float* __restrict__ Wr2, float* __restrict__ node_e,
    const float* __restrict__ Wu_next, __half* __restrict__ hu_out,
    float* __restrict__ h, int has_next,
    int do_mlp, const __half* __restrict__ ef,
    const float* __restrict__ W1n, const float* __restrict__ b1n,
    const _Float16* __restrict__ W2tn, const float* __restrict__ b2n,
    __half* __restrict__ hm2_next)
{
  // 18432 B pool: gather: rw f16[4][32*68] @0 (17408 B), elw int2[4][32] @17408
  //               epilogue overlay: al f32[512] @0, h2/out f32[512] @2048
  //               mlp blocks: hm1 f16[4][16*72] (9216 B)
  __shared__ float pool[4608];

  int b = blockIdx.x, t = threadIdx.x;
  if (do_mlp) {
    if (b < MLPB) {
      mlp_body(b, t, (_Float16*)pool, ef, W1n, b1n, W2tn, b2n, hm2_next);
      return;
    }
    b -= MLPB;
  }
  _Float16* rw_base = (_Float16*)pool;
  int2* elw_base = (int2*)((char*)pool + 17408);
  float* al_s = pool;
  float* h2_s = pool + 512;

  int n = (b & 7) * (NN/8) + (b >> 3);   // XCD-locality swizzle
  int beg = off[n], deg = off[n+1] - beg;

  int lane = t & 63, wv = t >> 6;
  int ln15 = lane & 15, quad = lane >> 4;
  _Float16* rww = rw_base + wv*(32*68);
  int2* elw = elw_base + wv*32;
  const _Float16* hm2h = (const _Float16*)hm2;
  const _Float16* Yh = (const _Float16*)Y;
  const _Float16* huh = (const _Float16*)hu_in;

  float hreg0 = h[(size_t)n*512 + t];
  float hreg1 = h[(size_t)n*512 + t + 256];

  int cl = lane >> 3, m0 = (lane & 7) * 2;
  int c = wv*8 + cl, cl4 = cl*4;
  int cl8 = lane & 56;
  int l0 = lof(m0), l1 = lof(m0 + 1);
  int eb0 = l0 & ~1;          // even base of the (l0,l1) half2
  int c0 = l0 - eb0;          // component selects (0/1)
  int c1 = l1 - eb0;
  float acc0 = 0.0f, acc1 = 0.0f;

  int2 el_cur = make_int2(0, 0);
  f16x8 aA0 = {}, aA1 = {}, aB0 = {}, aB1 = {};
  if (deg > 0) {
    int idx = lane < deg ? lane : deg - 1;
    el_cur = elist[beg + idx];
    int eA = __shfl(el_cur.x, ln15);
    int eB = __shfl(el_cur.x, 16 + ln15);
    aA0 = *(const f16x8*)(hm2h + (size_t)eA*64 + quad*8);
    aA1 = *(const f16x8*)(hm2h + (size_t)eA*64 + 32 + quad*8);
    aB0 = *(const f16x8*)(hm2h + (size_t)eB*64 + quad*8);
    aB1 = *(const f16x8*)(hm2h + (size_t)eB*64 + 32 + quad*8);
  }

  for (int base = 0; base < deg; base += 32) {
    int cnt = min(32, deg - base);
    if (lane < 32) elw[lane] = el_cur;

    #pragma unroll
    for (int cg = 0; cg < 4; ++cg) {
      int colg = (cg < 2) ? (wv*32 + cg*16 + ln15)
                          : (128 + wv*32 + (cg-2)*16 + ln15);
      f16x8 b0 = *(const f16x8*)(W3t + (size_t)colg*64 + quad*8);
      f16x8 b1v = *(const f16x8*)(W3t + (size_t)colg*64 + 32 + quad*8);
      f32x4 dA = {0.f, 0.f, 0.f, 0.f};
      dA = __builtin_amdgcn_mfma_f32_16x16x32_f16(aA0, b0, dA, 0, 0, 0);
      dA = __builtin_amdgcn_mfma_f32_16x16x32_f16(aA1, b1v, dA, 0, 0, 0);
      f32x4 dB = {0.f, 0.f, 0.f, 0.f};
      dB = __builtin_amdgcn_mfma_f32_16x16x32_f16(aB0, b0, dB, 0, 0, 0);
      dB = __builtin_amdgcn_mfma_f32_16x16x32_f16(aB1, b1v, dB, 0, 0, 0);
      #pragma unroll
      for (int r = 0; r < 4; ++r) {
        rww[(quad*4 + r)*68 + cg*16 + ln15]      = (_Float16)dA[r];
        rww[(16 + quad*4 + r)*68 + cg*16 + ln15] = (_Float16)dB[r];
      }
    }

    int2 el_nxt = el_cur;
    f16x8 nA0 = aA0, nA1 = aA1, nB0 = aB0, nB1 = aB1;
    if (base + 32 < deg) {
      int idx = base + 32 + lane;
      if (idx >= deg) idx = deg - 1;
      el_nxt = elist[beg + idx];
      int eA = __shfl(el_nxt.x, ln15);
      int eB = __shfl(el_nxt.x, 16 + ln15);
      nA0 = *(const f16x8*)(hm2h + (size_t)eA*64 + quad*8);
      nA1 = *(const f16x8*)(hm2h + (size_t)eA*64 + 32 + quad*8);
      nB0 = *(const f16x8*)(hm2h + (size_t)eB*64 + quad*8);
      nB1 = *(const f16x8*)(hm2h + (size_t)eB*64 + 32 + quad*8);
    }

    f16x2 accv = {(_Float16)0.f, (_Float16)0.f};
    #pragma unroll 8
    for (int i = 0; i < cnt; ++i) {
      int2 ed = elw[i];                               // ds_read_b64
      f16x2 hjm = *(const f16x2*)(huh + (size_t)ed.y*512 + c*16 + m0);
      int hj_i = __shfl(*(int*)&hjm, cl8);            // m0=0 lane of this c
      f16x2 hjv = *(f16x2*)&hj_i;
      f16x2 hj0v; hj0v[0] = hjv[0]; hj0v[1] = hjv[0];
      f16x2 Ym = *(const f16x2*)(Yh + (size_t)ed.x*16 + m0);
      f16x2 v0 = *(const f16x2*)&rww[i*68 + cl4 + eb0];        // ds_read_b32
      f16x2 v1 = *(const f16x2*)&rww[i*68 + 32 + cl4 + eb0];   // ds_read_b32
      f16x2 w0v; w0v[0] = c0 ? v0[1] : v0[0]; w0v[1] = c1 ? v0[1] : v0[0];
      f16x2 w1v; w1v[0] = c0 ? v1[1] : v1[0]; w1v[1] = c1 ? v1[1] : v1[0];
      accv += w0v * (Ym * hj0v) + w1v * hjm;
    }
    acc0 += (float)accv[0];
    acc1 += (float)accv[1];

    el_cur = el_nxt;
    aA0 = nA0; aA1 = nA1; aB0 = nB0; aB1 = nB1;
  }

  __syncthreads();   // tile phase done -> overlay safe

  al_s[c*16 + m0]     = acc0 * INV_AVG;
  al_s[c*16 + m0 + 1] = acc1 * INV_AVG;
  h2_s[t]       = hreg0;
  h2_s[t + 256] = hreg1;
  __syncthreads();

  int sp = species[n];
  float xn = xnode[n];
  int d = lane & 31, ch = lane >> 5;
  #pragma unroll
  for (int mi = 0; mi < 4; ++mi) {
    int m = wv*4 + mi;
    int l = lof(m);
    const float* wd  = Wd  + l*1024 + d;
    const float* wsc = Wsc + l*4096 + sp*32 + d;
    float a = 0.0f, s = 0.0f;
    #pragma unroll 4
    for (int cc = 0; cc < 16; ++cc) {
      int c2 = cc + ch*16;
      a += al_s[c2*16 + m] * wd[c2*32];
      s += h2_s[c2*16 + m] * wsc[c2*128];
    }
    a += __shfl_xor(a, 32);
    s += __shfl_xor(s, 32);
    float hn = a*xn + s;
    if (ch == 0) h2_s[d*16 + m] = hn;       // out overlay (wave-excl col)
    if (has_next) {
      const float* wu = Wu_next + l*1024 + d;
      float u = 0.0f;
      #pragma unroll 4
      for (int cc = 0; cc < 16; ++cc) {
        int c2 = cc + ch*16;
        u += h2_s[c2*16 + m] * wu[c2*32];    // reads out (same wave wrote)
      }
      u += __shfl_xor(u, 32);
      if (ch == 0) al_s[d*16 + m] = u;      // hu overlay (wave-excl col)
    }
  }

  if (t < 64) {
    float pre = br1[t];
    #pragma unroll 4
    for (int cc = 0; cc < CC; ++cc) pre += h2_s[cc*16] * Wr1[cc*64 + t];
    float v = siluf(pre) * Wr2[t];
    #pragma unroll
    for (int off2 = 32; off2 > 0; off2 >>= 1) v += __shfl_down(v, off2);
    if (t == 0) node_e[n] += siluf(v);
  }
  __syncthreads();   // out/hu complete

  h[(size_t)n*512 + t]       = h2_s[t];
  h[(size_t)n*512 + t + 256] = h2_s[t + 256];
  if (has_next) {
    __half2 o;
    o.x = __float2half(al_s[2*t]);
    o.y = __float2half(al_s[2*t + 1]);
    *(__half2*)(hu_out + (size_t)n*512 + 2*t) = o;
  }
}

// ---------------------------------------------------------------------------
// Kernel: per-graph sum of node energies
// ---------------------------------------------------------------------------
__global__ __launch_bounds__(128) void k_out(
    const float* __restrict__ node_e, float* __restrict__ out)
{
  int g = blockIdx.x, t = threadIdx.x;
  float v = (t < NPG) ? node_e[g*NPG + t] : 0.0f;
  #pragma unroll
  for (int off2 = 32; off2 > 0; off2 >>= 1) v += __shfl_down(v, off2);
  __shared__ float r2[2];
  if ((t & 63) == 0) r2[t >> 6] = v;
  __syncthreads();
  if (t == 0) out[g] = r2[0] + r2[1];
}

// Diagnostic: if workspace too small, report its size (MB) via absmax
__global__ void k_dbg(float* __restrict__ out, float v) {
  int i = blockIdx.x * 64 + threadIdx.x;
  if (i < GG) out[i] = v;
}

// ---------------------------------------------------------------------------
extern "C" void kernel_launch(void* const* d_in, const int* in_sizes, int n_in,
                              void* d_out, int out_size, void* d_ws, size_t ws_size,
                              hipStream_t stream)
{
  const float* positions = (const float*)d_in[0];
  const float* cell      = (const float*)d_in[1];
  const int*   Sij       = (const int*)d_in[2];
  const int*   eidx      = (const int*)d_in[3];
  const int*   species   = (const int*)d_in[4];
  const int*   batch     = (const int*)d_in[5];
  const float* W_emb     = (const float*)d_in[6];
  const float* W_xtp     = (const float*)d_in[7];
  const float* W_up      = (const float*)d_in[8];
  const float* W1        = (const float*)d_in[9];
  const float* b1        = (const float*)d_in[10];
  const float* W2        = (const float*)d_in[11];
  const float* b2        = (const float*)d_in[12];
  const float* W3        = (const float*)d_in[13];
  const float* W_down    = (const float*)d_in[14];
  const float* W_sc      = (const float*)d_in[15];
  const float* Wr1       = (const float*)d_in[16];
  const float* br1       = (const float*)d_in[17];
  const float* Wr2       = (const float*)d_in[18];
  float* out = (float*)d_out;
  (void)in_sizes; (void)n_in; (void)out_size;

  const size_t NEED_BASE  = 120000000;
  const size_t NEED_FUSED = 166500000;
  if (ws_size < NEED_BASE) {
    k_dbg<<<dim3(2), dim3(64), 0, stream>>>(out, (float)(ws_size >> 20));
    return;
  }
  const bool fused = ws_size >= NEED_FUSED;

  char* ws = (char*)d_ws;
  size_t off = 0;
  auto alloc = [&](size_t bytes) -> void* {
    void* p = ws + off;
    off += (bytes + 255) & ~(size_t)255;
    return p;
  };
  __half*    Yb      = (__half*)alloc((size_t)EE*16*2);  // 12.8 MB
  __half*    efb     = (__half*)alloc((size_t)EE*8*2);   //  6.4 MB
  float*     hb      = (float*)alloc((size_t)NN*512*4);  // 20.5 MB
  __half*    huA     = (__half*)alloc((size_t)NN*512*2); // 10.2 MB
  __half*    huB     = (__half*)alloc((size_t)NN*512*2); // 10.2 MB
  float*     xnodeb  = (float*)alloc((size_t)NN*4);
  float*     node_eb = (float*)alloc((size_t)NN*4);
  int*       offb    = (int*)alloc((size_t)(NN+1)*4);
  int*       curb    = (int*)alloc((size_t)NN*4);
  int2*      elistb  = (int2*)alloc((size_t)EE*8);       //  3.2 MB
  _Float16*  W2tb    = (_Float16*)alloc((size_t)NLAYER*64*64*2);
  _Float16*  W3tb    = (_Float16*)alloc((size_t)NLAYER*64*256*2);
  __half*    hm2A    = (__half*)alloc((size_t)EE*64*2);  // 51.2 MB
  __half*    hm2B    = fused ? (__half*)alloc((size_t)EE*64*2) : hm2A;

  dim3 blk(256);
  hipMemsetAsync(curb, 0, (size_t)NN*4, stream);
  k_pre<<<dim3(4568), blk, 0, stream>>>(positions, cell, Sij, eidx, batch,
      Yb, efb, species, W_emb, W_xtp, hb, xnodeb, node_eb,
      W2, W3, W2tb, W3tb, curb);
  k_csr_scan<<<dim3(GG), dim3(128), 0, stream>>>(curb, offb, curb);
  k_csr_fill<<<dim3((EE + 255)/256), blk, 0, stream>>>(eidx, curb, elistb);

  // layer-0 hu + layer-0 mlp (fused blocks)
  k_humlp<<<dim3(MLPB + NN), blk, 0, stream>>>(hb, W_up + 0*4096, huA,
      efb, W1 + 0, b1 + 0, W2tb + 0, b2 + 0, hm2A);

  __half* hin = huA; __half* hout = huB;
  __half* hm2_cur = hm2A; __half* hm2_nxt = hm2B;
  for (int layer = 0; layer < NLAYER; ++layer) {
    int has_next = (layer + 1 < NLAYER) ? 1 : 0;
    int do_mlp = (fused && has_next) ? 1 : 0;
    int nl = has_next ? layer + 1 : 0;
    k_gather<<<dim3(NN + (do_mlp ? MLPB : 0)), blk, 0, stream>>>(
        elistb, offb, Yb, hm2_cur,
        W3tb + layer*16384, hin,
        species, xnodeb,
        W_down + layer*4096, W_sc + layer*16384,
        Wr1 + layer*CC*64, br1 + layer*64, Wr2 + layer*64, node_eb,
        W_up + (has_next ? (layer+1)*4096 : 0), hout, hb, has_next,
        do_mlp, efb,
        W1 + nl*NBES*64, b1 + nl*64, W2tb + nl*4096, b2 + nl*64,
        hm2_nxt);
    if (!fused && has_next) {
      k_mlp<<<dim3(MLPB), blk, 0, stream>>>(efb,
          W1 + (layer+1)*NBES*64, b1 + (layer+1)*64,
          W2tb + (layer+1)*4096, b2 + (layer+1)*64, hm2A);
    }
    __half* tmp = hin; hin = hout; hout = tmp;
    if (fused) { __half* t2 = hm2_cur; hm2_cur = hm2_nxt; hm2_nxt = t2; }
  }
  k_out<<<dim3(GG), dim3(128), 0, stream>>>(node_eb, out);
}

// Round 14
// 1051.898 us; speedup vs baseline: 1.4259x; 1.0009x over previous
//
#include <hip/hip_runtime.h>
#include <hip/hip_bf16.h>
#include <hip/hip_fp16.h>
#include <stdint.h>

// Problem constants (match reference)
#define NN   10000
#define GG   100
#define NPG  100
#define EE   400000
#define EPG  4000
#define CC   32
#define LM   16
#define SS   4
#define NBES 8
#define NLAYER 3
#define INV_AVG (1.0f/40.0f)
#define MLPB 6256   // mlp block count (8*782 >= EE/64)

typedef _Float16 f16x8 __attribute__((ext_vector_type(8)));
typedef _Float16 f16x4 __attribute__((ext_vector_type(4)));
typedef _Float16 f16x2 __attribute__((ext_vector_type(2)));
typedef float    f32x4 __attribute__((ext_vector_type(4)));

__device__ __forceinline__ float siluf(float x) { return x / (1.0f + __expf(-x)); }
__device__ __forceinline__ int lof(int m) { return (m >= 1) + (m >= 4) + (m >= 9); }

// ---------------------------------------------------------------------------
// geometry body (per edge): Y[E,16] f16, ef[E,8] f16
// ---------------------------------------------------------------------------
__device__ __forceinline__ void geom_body(
    int e, const float* __restrict__ pos, const float* __restrict__ cell,
    const int* __restrict__ Sij, const int* __restrict__ eidx,
    const int* __restrict__ batch, __half* __restrict__ Y, __half* __restrict__ ef)
{
  int ia = eidx[e], ja = eidx[EE + e];
  int g = batch[ia];
  float s0 = (float)Sij[e*3+0], s1 = (float)Sij[e*3+1], s2 = (float)Sij[e*3+2];
  const float* cg = cell + g*9;
  float shx = s0*cg[0] + s1*cg[3] + s2*cg[6];
  float shy = s0*cg[1] + s1*cg[4] + s2*cg[7];
  float shz = s0*cg[2] + s1*cg[5] + s2*cg[8];
  float rx = (pos[ja*3+0] - pos[ia*3+0] + shx) / 6.0f;
  float ry = (pos[ja*3+1] - pos[ia*3+1] + shy) / 6.0f;
  float rz = (pos[ja*3+2] - pos[ia*3+2] + shz) / 6.0f;
  float r2 = rx*rx + ry*ry + rz*rz;
  float r  = sqrtf(r2);
  float rs = (r > 1e-9f) ? r : 1e-9f;
  float inv = 1.0f / rs;
  float x = rx*inv, y = ry*inv, z = rz*inv;

  const float s3   = 1.7320508075688772f;
  const float s15  = 3.872983346207417f;
  const float s5h  = 1.118033988749895f;
  const float s15h = 1.9364916731037085f;
  const float s358 = 2.091650066335189f;
  const float s105 = 10.246950765959598f;
  const float s218 = 1.620185174601965f;
  const float s7h  = 1.3228756555322954f;
  const float s105h= 5.123475382979799f;

  float xx = x*x, yy = y*y, zz = z*z;
  float yv[16];
  yv[0]  = 1.0f;
  yv[1]  = s3*x;  yv[2] = s3*y;  yv[3] = s3*z;
  yv[4]  = s15*x*y; yv[5] = s15*y*z; yv[6] = s5h*(3.0f*zz - 1.0f);
  yv[7]  = s15*x*z; yv[8] = s15h*(xx - yy);
  yv[9]  = s358*y*(3.0f*xx - yy);
  yv[10] = s105*x*y*z;
  yv[11] = s218*y*(5.0f*zz - 1.0f);
  yv[12] = s7h*(5.0f*zz*z - 3.0f*z);
  yv[13] = s218*x*(5.0f*zz - 1.0f);
  yv[14] = s105h*z*(xx - yy);
  yv[15] = s358*x*(xx - 3.0f*yy);

  union { __half h[16]; uint4 u[2]; } yp;
  #pragma unroll
  for (int i = 0; i < 16; ++i) yp.h[i] = __float2half(yv[i]);
  uint4* Yp = (uint4*)(Y + (size_t)e*16);
  Yp[0] = yp.u[0];
  Yp[1] = yp.u[1];

  float f = 0.0f;
  if (r < 1.0f) f = 1.0f - 6.0f*r2 + 8.0f*r2*r - 3.0f*r2*r2;
  float c1 = 1.4142135623730951f * f * inv;
  float ang = 3.14159265358979323846f * rs;
  float sn = __sinf(ang), cn = __cosf(ang);
  float twoc = 2.0f * cn;
  float sprev = 0.0f, scur = sn;
  union { __half h[8]; uint4 u; } p;
  #pragma unroll
  for (int n1 = 1; n1 <= NBES; ++n1) {
    p.h[n1-1] = __float2half(c1 * scur);
    float snext = twoc * scur - sprev;
    sprev = scur; scur = snext;
  }
  *(uint4*)(ef + (size_t)e*8) = p.u;
}

// ---------------------------------------------------------------------------
// k_pre: geom (1563) | init (1250) | wconv (192) | csr_count (1563)
// ---------------------------------------------------------------------------
__global__ __launch_bounds__(256) void k_pre(
    const float* __restrict__ pos, const float* __restrict__ cell,
    const int* __restrict__ Sij, const int* __restrict__ eidx,
    const int* __restrict__ batch, __half* __restrict__ Y, __half* __restrict__ ef,
    const int* __restrict__ species, const float* __restrict__ W_emb,
    const float* __restrict__ W_xtp, float* __restrict__ h,
    float* __restrict__ xnode, float* __restrict__ node_e,
    const float* __restrict__ W2, const float* __restrict__ W3,
    _Float16* __restrict__ W2t, _Float16* __restrict__ W3t,
    int* __restrict__ cnt)
{
  int b = blockIdx.x, t = threadIdx.x;
  if (b < 1563) {
    int e = b*256 + t;
    if (e < EE) geom_body(e, pos, cell, Sij, eidx, batch, Y, ef);
  } else if (b < 2813) {
    int idx = (b - 1563)*256 + t;
    if (idx < NN*CC) {
      int n = idx / CC, c = idx % CC;
      int sp = species[n];
      float h0 = W_emb[sp*CC + c];
      float* hp = h + (size_t)n*512 + c*16;
      hp[0] = h0;
      #pragma unroll
      for (int m = 1; m < 16; ++m) hp[m] = 0.0f;
      if (c == 0) {
        float xn = 0.0f;
        for (int c2 = 0; c2 < CC; ++c2) xn += W_emb[sp*CC + c2] * W_xtp[c2*SS + sp];
        xnode[n] = xn;
        node_e[n] = 0.0f;
      }
    }
  } else if (b < 3005) {
    int idx = (b - 2813)*256 + t;
    if (idx < NLAYER*64*64) {
      int l = idx / 4096, rem = idx % 4096, k = rem / 64, j = rem % 64;
      W2t[l*4096 + j*64 + k] = (_Float16)W2[idx];
    }
    if (idx < NLAYER*64*256) {
      int l = idx / 16384, rem = idx % 16384, k = rem / 256, j = rem % 256;
      W3t[l*16384 + j*64 + k] = (_Float16)W3[idx];
    }
  } else {
    int e = (b - 3005)*256 + t;
    if (e < EE) atomicAdd(&cnt[eidx[e]], 1);
  }
}

// ---------------------------------------------------------------------------
// CSR scan + fill
// ---------------------------------------------------------------------------
__global__ __launch_bounds__(128) void k_csr_scan(
    const int* __restrict__ cnt, int* __restrict__ off, int* __restrict__ cursor) {
  __shared__ int s[128];
  int g = blockIdx.x, t = threadIdx.x;
  int own = (t < NPG) ? cnt[g*NPG + t] : 0;
  s[t] = own;
  __syncthreads();
  #pragma unroll
  for (int d = 1; d < 128; d <<= 1) {
    int v = (t >= d) ? s[t-d] : 0;
    __syncthreads();
    s[t] += v;
    __syncthreads();
  }
  if (t < NPG) {
    int o = g*EPG + s[t] - own;
    off[g*NPG + t] = o;
    cursor[g*NPG + t] = o;
    if (g == GG-1 && t == NPG-1) off[NN] = EE;
  }
}

__global__ __launch_bounds__(256) void k_csr_fill(
    const int* __restrict__ eidx, int* __restrict__ cursor, int2* __restrict__ elist) {
  int e = blockIdx.x * 256 + threadIdx.x;
  if (e >= EE) return;
  int ia = eidx[e], ja = eidx[EE + e];
  int pos = atomicAdd(&cursor[ia], 1);
  elist[pos] = make_int2(e, ja);
}

// ---------------------------------------------------------------------------
// mlp body (per block of 64 edges): ef(8)->hm1(64) VALU -> hm2(64) MFMA f16
// ---------------------------------------------------------------------------
__device__ __forceinline__ void mlp_body(
    int mb, int t, _Float16* pool16,
    const __half* __restrict__ ef, const float* __restrict__ W1,
    const float* __restrict__ b1, const _Float16* __restrict__ W2t,
    const float* __restrict__ b2, __half* __restrict__ hm2)
{
  int eb = (mb & 7) * 782 + (mb >> 3);
  if (eb >= EE/64) return;
  int wv = t >> 6, lane = t & 63;
  int ln15 = lane & 15, quad = lane >> 4;
  _Float16* hm1 = pool16 + wv*(16*72);
  size_t e16 = (size_t)eb*64 + wv*16;

  union { uint4 u; __half hh[8]; } efv;
  efv.u = *(const uint4*)(ef + (e16 + ln15)*8);
  float ev[8];
  #pragma unroll
  for (int k = 0; k < 8; ++k) ev[k] = __half2float(efv.hh[k]);
  #pragma unroll
  for (int p = 0; p < 4; ++p) {
    int j0 = p*16 + quad*4;
    float4 a = *(const float4*)(b1 + j0);
    #pragma unroll
    for (int k = 0; k < 8; ++k) {
      const float4 w = *(const float4*)(W1 + k*64 + j0);
      a.x += ev[k]*w.x; a.y += ev[k]*w.y; a.z += ev[k]*w.z; a.w += ev[k]*w.w;
    }
    f16x4 pk;
    pk[0] = (_Float16)siluf(a.x);
    pk[1] = (_Float16)siluf(a.y);
    pk[2] = (_Float16)siluf(a.z);
    pk[3] = (_Float16)siluf(a.w);
    *(f16x4*)&hm1[ln15*72 + j0] = pk;
  }

  f16x8 a0 = *(const f16x8*)(hm1 + ln15*72 + quad*8);
  f16x8 a1 = *(const f16x8*)(hm1 + ln15*72 + 32 + quad*8);
  #pragma unroll
  for (int cg = 0; cg < 4; ++cg) {
    int col = cg*16 + ln15;
    f32x4 d = {0.f, 0.f, 0.f, 0.f};
    d = __builtin_amdgcn_mfma_f32_16x16x32_f16(a0, *(const f16x8*)(W2t + (size_t)col*64 + quad*8), d, 0, 0, 0);
    d = __builtin_amdgcn_mfma_f32_16x16x32_f16(a1, *(const f16x8*)(W2t + (size_t)col*64 + 32 + quad*8), d, 0, 0, 0);
    float bb = b2[col];
    #pragma unroll
    for (int r = 0; r < 4; ++r)
      hm2[(e16 + quad*4 + r)*64 + col] = __float2half(siluf(d[r] + bb));
  }
}

// standalone mlp (fallback path)
__global__ __launch_bounds__(256) void k_mlp(
    const __half* __restrict__ ef, const float* __restrict__ W1,
    const float* __restrict__ b1, const _Float16* __restrict__ W2t,
    const float* __restrict__ b2, __half* __restrict__ hm2)
{
  __shared__ _Float16 pool16[4*16*72];
  mlp_body(blockIdx.x, threadIdx.x, pool16, ef, W1, b1, W2t, b2, hm2);
}

// ---------------------------------------------------------------------------
// k_humlp: blocks [0,MLPB) run layer-0 mlp; blocks [MLPB, MLPB+NN) run hu.
// ---------------------------------------------------------------------------
__global__ __launch_bounds__(256) void k_humlp(
    const float* __restrict__ h, const float* __restrict__ Wu,
    __half* __restrict__ hu,
    const __half* __restrict__ ef, const float* __restrict__ W1,
    const float* __restrict__ b1, const _Float16* __restrict__ W2t,
    const float* __restrict__ b2, __half* __restrict__ hm2)
{
  __shared__ float pool[1152];
  int b = blockIdx.x, t = threadIdx.x;
  if (b < MLPB) {
    __shared__ _Float16 pool16[4*16*72];
    mlp_body(b, t, pool16, ef, W1, b1, W2t, b2, hm2);
    return;
  }
  int n = b - MLPB;
  float* h_s = pool;
  float* hu_s = pool + 512;
  h_s[t]       = h[(size_t)n*512 + t];
  h_s[t + 256] = h[(size_t)n*512 + t + 256];
  __syncthreads();
  int lane = t & 63, wv = t >> 6;
  int d = lane & 31, ch = lane >> 5;
  #pragma unroll
  for (int mi = 0; mi < 4; ++mi) {
    int m = wv*4 + mi;
    int l = lof(m);
    const float* wu = Wu + l*1024 + d;
    float u = 0.0f;
    #pragma unroll 4
    for (int cc = 0; cc < 16; ++cc) {
      int c = cc + ch*16;
      u += h_s[c*16 + m] * wu[c*32];
    }
    u += __shfl_xor(u, 32);
    if (ch == 0) hu_s[d*16 + m] = u;
  }
  __syncthreads();
  __half2 o;
  o.x = __float2half(hu_s[2*t]);
  o.y = __float2half(hu_s[2*t + 1]);
  *(__half2*)(hu + (size_t)n*512 + 2*t) = o;
}

// ---------------------------------------------------------------------------
// k_gather: optional fused next-layer mlp blocks first (do_mlp), then
// block-per-node gather (R13 body + v_perm selects + deeper unroll).
// ---------------------------------------------------------------------------
__global__ __launch_bounds__(256) void k_gather(
    const int2* __restrict__ elist, const int* __restrict__ off,
    const __half* __restrict__ Y, const __half* __restrict__ hm2,
    const _Float16* __restrict__ W3t, const __half* __restrict__ hu_in,
    const int* __restrict__ species, const float* __restrict__ xnode,
    const float* __restrict__ Wd, const float* __restrict__ Wsc,
    const float* __restrict__ Wr1, const float* __restrict__ br1,
    const float* __restrict__ Wr2, float* __restrict__ node_e,
    const float* __restrict__ Wu_next, __half* __restrict__ hu_out,
    float* __restrict__ h, int has_next,
    int do_mlp, const __half* __restrict__ ef,
    const float* __restrict__ W1n, const float* __restrict__ b1n,
    const _Float16* __restrict__ W2tn, const float* __restrict__ b2n,
    __half* __restrict__ hm2_next)
{
  __shared__ float pool[4608];

  int b = blockIdx.x, t = threadIdx.x;
  if (do_mlp) {
    if (b < MLPB) {
      mlp_body(b, t, (_Float16*)pool, ef, W1n, b1n, W2tn, b2n, hm2_next);
      return;
    }
    b -= MLPB;
  }
  _Float16* rw_base = (_Float16*)pool;
  int2* elw_base = (int2*)((char*)pool + 17408);
  float* al_s = pool;
  float* h2_s = pool + 512;

  int n = (b & 7) * (NN/8) + (b >> 3);   // XCD-locality swizzle
  int beg = off[n], deg = off[n+1] - beg;

  int lane = t & 63, wv = t >> 6;
  int ln15 = lane & 15, quad = lane >> 4;
  _Float16* rww = rw_base + wv*(32*68);
  int2* elw = elw_base + wv*32;
  const _Float16* hm2h = (const _Float16*)hm2;
  const _Float16* Yh = (const _Float16*)Y;
  const _Float16* huh = (const _Float16*)hu_in;

  float hreg0 = h[(size_t)n*512 + t];
  float hreg1 = h[(size_t)n*512 + t + 256];

  int cl = lane >> 3, m0 = (lane & 7) * 2;
  int c = wv*8 + cl, cl4 = cl*4;
  int cl8 = lane & 56;
  int l0 = lof(m0), l1 = lof(m0 + 1);
  int eb0 = l0 & ~1;          // even base of the (l0,l1) half2
  int c0 = l0 - eb0;          // component selects (0/1)
  int c1 = l1 - eb0;
  // byte-selector for v_perm: result halfs = (v[c0], v[c1])
  unsigned selm = (unsigned)(c0*2) | ((unsigned)(c0*2+1) << 8)
                | ((unsigned)(c1*2) << 16) | ((unsigned)(c1*2+1) << 24);
  float acc0 = 0.0f, acc1 = 0.0f;

  int2 el_cur = make_int2(0, 0);
  f16x8 aA0 = {}, aA1 = {}, aB0 = {}, aB1 = {};
  if (deg > 0) {
    int idx = lane < deg ? lane : deg - 1;
    el_cur = elist[beg + idx];
    int eA = __shfl(el_cur.x, ln15);
    int eB = __shfl(el_cur.x, 16 + ln15);
    aA0 = *(const f16x8*)(hm2h + (size_t)eA*64 + quad*8);
    aA1 = *(const f16x8*)(hm2h + (size_t)eA*64 + 32 + quad*8);
    aB0 = *(const f16x8*)(hm2h + (size_t)eB*64 + quad*8);
    aB1 = *(const f16x8*)(hm2h + (size_t)eB*64 + 32 + quad*8);
  }

  for (int base = 0; base < deg; base += 32) {
    int cnt = min(32, deg - base);
    if (lane < 32) elw[lane] = el_cur;

    #pragma unroll
    for (int cg = 0; cg < 4; ++cg) {
      int colg = (cg < 2) ? (wv*32 + cg*16 + ln15)
                          : (128 + wv*32 + (cg-2)*16 + ln15);
      f16x8 b0 = *(const f16x8*)(W3t + (size_t)colg*64 + quad*8);
      f16x8 b1v = *(const f16x8*)(W3t + (size_t)colg*64 + 32 + quad*8);
      f32x4 dA = {0.f, 0.f, 0.f, 0.f};
      dA = __builtin_amdgcn_mfma_f32_16x16x32_f16(aA0, b0, dA, 0, 0, 0);
      dA = __builtin_amdgcn_mfma_f32_16x16x32_f16(aA1, b1v, dA, 0, 0, 0);
      f32x4 dB = {0.f, 0.f, 0.f, 0.f};
      dB = __builtin_amdgcn_mfma_f32_16x16x32_f16(aB0, b0, dB, 0, 0, 0);
      dB = __builtin_amdgcn_mfma_f32_16x16x32_f16(aB1, b1v, dB, 0, 0, 0);
      #pragma unroll
      for (int r = 0; r < 4; ++r) {
        rww[(quad*4 + r)*68 + cg*16 + ln15]      = (_Float16)dA[r];
        rww[(16 + quad*4 + r)*68 + cg*16 + ln15] = (_Float16)dB[r];
      }
    }

    int2 el_nxt = el_cur;
    f16x8 nA0 = aA0, nA1 = aA1, nB0 = aB0, nB1 = aB1;
    if (base + 32 < deg) {
      int idx = base + 32 + lane;
      if (idx >= deg) idx = deg - 1;
      el_nxt = elist[beg + idx];
      int eA = __shfl(el_nxt.x, ln15);
      int eB = __shfl(el_nxt.x, 16 + ln15);
      nA0 = *(const f16x8*)(hm2h + (size_t)eA*64 + quad*8);
      nA1 = *(const f16x8*)(hm2h + (size_t)eA*64 + 32 + quad*8);
      nB0 = *(const f16x8*)(hm2h + (size_t)eB*64 + quad*8);
      nB1 = *(const f16x8*)(hm2h + (size_t)eB*64 + 32 + quad*8);
    }

    f16x2 accv = {(_Float16)0.f, (_Float16)0.f};
    #pragma unroll 16
    for (int i = 0; i < cnt; ++i) {
      int2 ed = elw[i];                               // ds_read_b64
      f16x2 hjm = *(const f16x2*)(huh + (size_t)ed.y*512 + c*16 + m0);
      int hj_i = __shfl(*(int*)&hjm, cl8);            // m0=0 lane of this c
      f16x2 hjv = *(f16x2*)&hj_i;
      f16x2 hj0v; hj0v[0] = hjv[0]; hj0v[1] = hjv[0];
      f16x2 Ym = *(const f16x2*)(Yh + (size_t)ed.x*16 + m0);
      unsigned v0i = *(const unsigned*)&rww[i*68 + cl4 + eb0];
      unsigned v1i = *(const unsigned*)&rww[i*68 + 32 + cl4 + eb0];
      unsigned w0i = __builtin_amdgcn_perm(v0i, v0i, selm);   // v_perm_b32
      unsigned w1i = __builtin_amdgcn_perm(v1i, v1i, selm);
      f16x2 w0v = *(f16x2*)&w0i;
      f16x2 w1v = *(f16x2*)&w1i;
      accv += w0v * (Ym * hj0v) + w1v * hjm;
    }
    acc0 += (float)accv[0];
    acc1 += (float)accv[1];

    el_cur = el_nxt;
    aA0 = nA0; aA1 = nA1; aB0 = nB0; aB1 = nB1;
  }

  __syncthreads();   // tile phase done -> overlay safe

  al_s[c*16 + m0]     = acc0 * INV_AVG;
  al_s[c*16 + m0 + 1] = acc1 * INV_AVG;
  h2_s[t]       = hreg0;
  h2_s[t + 256] = hreg1;
  __syncthreads();

  int sp = species[n];
  float xn = xnode[n];
  int d = lane & 31, ch = lane >> 5;
  #pragma unroll
  for (int mi = 0; mi < 4; ++mi) {
    int m = wv*4 + mi;
    int l = lof(m);
    const float* wd  = Wd  + l*1024 + d;
    const float* wsc = Wsc + l*4096 + sp*32 + d;
    float a = 0.0f, s = 0.0f;
    #pragma unroll 4
    for (int cc = 0; cc < 16; ++cc) {
      int c2 = cc + ch*16;
      a += al_s[c2*16 + m] * wd[c2*32];
      s += h2_s[c2*16 + m] * wsc[c2*128];
    }
    a += __shfl_xor(a, 32);
    s += __shfl_xor(s, 32);
    float hn = a*xn + s;
    if (ch == 0) h2_s[d*16 + m] = hn;       // out overlay (wave-excl col)
    if (has_next) {
      const float* wu = Wu_next + l*1024 + d;
      float u = 0.0f;
      #pragma unroll 4
      for (int cc = 0; cc < 16; ++cc) {
        int c2 = cc + ch*16;
        u += h2_s[c2*16 + m] * wu[c2*32];    // reads out (same wave wrote)
      }
      u += __shfl_xor(u, 32);
      if (ch == 0) al_s[d*16 + m] = u;      // hu overlay (wave-excl col)
    }
  }

  if (t < 64) {
    float pre = br1[t];
    #pragma unroll 4
    for (int cc = 0; cc < CC; ++cc) pre += h2_s[cc*16] * Wr1[cc*64 + t];
    float v = siluf(pre) * Wr2[t];
    #pragma unroll
    for (int off2 = 32; off2 > 0; off2 >>= 1) v += __shfl_down(v, off2);
    if (t == 0) node_e[n] += siluf(v);
  }
  __syncthreads();   // out/hu complete

  h[(size_t)n*512 + t]       = h2_s[t];
  h[(size_t)n*512 + t + 256] = h2_s[t + 256];
  if (has_next) {
    __half2 o;
    o.x = __float2half(al_s[2*t]);
    o.y = __float2half(al_s[2*t + 1]);
    *(__half2*)(hu_out + (size_t)n*512 + 2*t) = o;
  }
}

// ---------------------------------------------------------------------------
// Kernel: per-graph sum of node energies
// ---------------------------------------------------------------------------
__global__ __launch_bounds__(128) void k_out(
    const float* __restrict__ node_e, float* __restrict__ out)
{
  int g = blockIdx.x, t = threadIdx.x;
  float v = (t < NPG) ? node_e[g*NPG + t] : 0.0f;
  #pragma unroll
  for (int off2 = 32; off2 > 0; off2 >>= 1) v += __shfl_down(v, off2);
  __shared__ float r2[2];
  if ((t & 63) == 0) r2[t >> 6] = v;
  __syncthreads();
  if (t == 0) out[g] = r2[0] + r2[1];
}

// Diagnostic: if workspace too small, report its size (MB) via absmax
__global__ void k_dbg(float* __restrict__ out, float v) {
  int i = blockIdx.x * 64 + threadIdx.x;
  if (i < GG) out[i] = v;
}

// ---------------------------------------------------------------------------
extern "C" void kernel_launch(void* const* d_in, const int* in_sizes, int n_in,
                              void* d_out, int out_size, void* d_ws, size_t ws_size,
                              hipStream_t stream)
{
  const float* positions = (const float*)d_in[0];
  const float* cell      = (const float*)d_in[1];
  const int*   Sij       = (const int*)d_in[2];
  const int*   eidx      = (const int*)d_in[3];
  const int*   species   = (const int*)d_in[4];
  const int*   batch     = (const int*)d_in[5];
  const float* W_emb     = (const float*)d_in[6];
  const float* W_xtp     = (const float*)d_in[7];
  const float* W_up      = (const float*)d_in[8];
  const float* W1        = (const float*)d_in[9];
  const float* b1        = (const float*)d_in[10];
  const float* W2        = (const float*)d_in[11];
  const float* b2        = (const float*)d_in[12];
  const float* W3        = (const float*)d_in[13];
  const float* W_down    = (const float*)d_in[14];
  const float* W_sc      = (const float*)d_in[15];
  const float* Wr1       = (const float*)d_in[16];
  const float* br1       = (const float*)d_in[17];
  const float* Wr2       = (const float*)d_in[18];
  float* out = (float*)d_out;
  (void)in_sizes; (void)n_in; (void)out_size;

  const size_t NEED_BASE  = 120000000;
  const size_t NEED_FUSED = 166500000;
  if (ws_size < NEED_BASE) {
    k_dbg<<<dim3(2), dim3(64), 0, stream>>>(out, (float)(ws_size >> 20));
    return;
  }
  const bool fused = ws_size >= NEED_FUSED;

  char* ws = (char*)d_ws;
  size_t off = 0;
  auto alloc = [&](size_t bytes) -> void* {
    void* p = ws + off;
    off += (bytes + 255) & ~(size_t)255;
    return p;
  };
  __half*    Yb      = (__half*)alloc((size_t)EE*16*2);  // 12.8 MB
  __half*    efb     = (__half*)alloc((size_t)EE*8*2);   //  6.4 MB
  float*     hb      = (float*)alloc((size_t)NN*512*4);  // 20.5 MB
  __half*    huA     = (__half*)alloc((size_t)NN*512*2); // 10.2 MB
  __half*    huB     = (__half*)alloc((size_t)NN*512*2); // 10.2 MB
  float*     xnodeb  = (float*)alloc((size_t)NN*4);
  float*     node_eb = (float*)alloc((size_t)NN*4);
  int*       offb    = (int*)alloc((size_t)(NN+1)*4);
  int*       curb    = (int*)alloc((size_t)NN*4);
  int2*      elistb  = (int2*)alloc((size_t)EE*8);       //  3.2 MB
  _Float16*  W2tb    = (_Float16*)alloc((size_t)NLAYER*64*64*2);
  _Float16*  W3tb    = (_Float16*)alloc((size_t)NLAYER*64*256*2);
  __half*    hm2A    = (__half*)alloc((size_t)EE*64*2);  // 51.2 MB
  __half*    hm2B    = fused ? (__half*)alloc((size_t)EE*64*2) : hm2A;

  dim3 blk(256);
  hipMemsetAsync(curb, 0, (size_t)NN*4, stream);
  k_pre<<<dim3(4568), blk, 0, stream>>>(positions, cell, Sij, eidx, batch,
      Yb, efb, species, W_emb, W_xtp, hb, xnodeb, node_eb,
      W2, W3, W2tb, W3tb, curb);
  k_csr_scan<<<dim3(GG), dim3(128), 0, stream>>>(curb, offb, curb);
  k_csr_fill<<<dim3((EE + 255)/256), blk, 0, stream>>>(eidx, curb, elistb);

  // layer-0 hu + layer-0 mlp (fused blocks)
  k_humlp<<<dim3(MLPB + NN), blk, 0, stream>>>(hb, W_up + 0*4096, huA,
      efb, W1 + 0, b1 + 0, W2tb + 0, b2 + 0, hm2A);

  __half* hin = huA; __half* hout = huB;
  __half* hm2_cur = hm2A; __half* hm2_nxt = hm2B;
  for (int layer = 0; layer < NLAYER; ++layer) {
    int has_next = (layer + 1 < NLAYER) ? 1 : 0;
    int do_mlp = (fused && has_next) ? 1 : 0;
    int nl = has_next ? layer + 1 : 0;
    k_gather<<<dim3(NN + (do_mlp ? MLPB : 0)), blk, 0, stream>>>(
        elistb, offb, Yb, hm2_cur,
        W3tb + layer*16384, hin,
        species, xnodeb,
        W_down + layer*4096, W_sc + layer*16384,
        Wr1 + layer*CC*64, br1 + layer*64, Wr2 + layer*64, node_eb,
        W_up + (has_next ? (layer+1)*4096 : 0), hout, hb, has_next,
        do_mlp, efb,
        W1 + nl*NBES*64, b1 + nl*64, W2tb + nl*4096, b2 + nl*64,
        hm2_nxt);
    if (!fused && has_next) {
      k_mlp<<<dim3(MLPB), blk, 0, stream>>>(efb,
          W1 + (layer+1)*NBES*64, b1 + (layer+1)*64,
          W2tb + (layer+1)*4096, b2 + (layer+1)*64, hm2A);
    }
    __half* tmp = hin; hin = hout; hout = tmp;
    if (fused) { __half* t2 = hm2_cur; hm2_cur = hm2_nxt; hm2_nxt = t2; }
  }
  k_out<<<dim3(GG), dim3(128), 0, stream>>>(node_eb, out);
}